// Round 2
// baseline (1588.586 us; speedup 1.0000x reference)
//
#include <hip/hip_runtime.h>
#include <hip/hip_bf16.h>

#define GG 128
#define SLOPE 0.01f

__device__ __forceinline__ float lrelu(float v) { return v > 0.f ? v : SLOPE * v; }
__device__ __forceinline__ float b2f(__hip_bfloat16 v) { return __bfloat162float(v); }

// dtype-flexible load/store: isf=1 -> buffer holds f32, isf=0 -> bf16
__device__ __forceinline__ float ldf(const void* p, int i, int isf) {
    if (isf) return ((const float*)p)[i];
    return __bfloat162float(((const __hip_bfloat16*)p)[i]);
}
__device__ __forceinline__ void stf(void* p, int i, float v, int isf) {
    if (isf) ((float*)p)[i] = v;
    else ((__hip_bfloat16*)p)[i] = __float2bfloat16(v);
}

// ---------------- dtype detection ----------------
// Inspect Wm (n elements) as bf16 half-words. Real bf16 weights (~0.1 scale)
// never have exponent >= 141 (|v| >= 16384). f32 data read as bf16 has ~n/2
// mantissa half-words with random exponent bits -> detection certain.
// Also sets flag[32] = 1 (the "always f32" flag used for staged weights).
__global__ void k_detect(const unsigned short* __restrict__ w, int n, int* __restrict__ flag) {
    __shared__ int bad;
    if (threadIdx.x == 0) bad = 0;
    __syncthreads();
    for (int t = threadIdx.x; t < n; t += 256) {
        unsigned short u = w[t];
        int e = (u >> 7) & 0xFF;
        if (e >= 141) bad = 1;  // benign same-value race
    }
    __syncthreads();
    if (threadIdx.x == 0) { flag[0] = bad; flag[32] = 1; }
}

// generic elementwise convert (possibly-bf16/possibly-f32 -> f32)
__global__ void k_cvt(const void* __restrict__ src, float* __restrict__ dst, int n,
                      const int* __restrict__ dtf) {
    int isf = *dtf;
    int i = blockIdx.x * 256 + threadIdx.x;
    if (i < n) dst[i] = ldf(src, i, isf);
}

// ---------------- embed: x = lrelu(nf * W_embed + b_embed) ----------------
__global__ void k_embed(const void* __restrict__ nf, const void* __restrict__ We,
                        const void* __restrict__ be, float* __restrict__ x, int N,
                        const int* __restrict__ dtf) {
    int isf = *dtf;
    int idx = blockIdx.x * 256 + threadIdx.x;
    if (idx >= N * 32) return;
    int n = idx >> 5, j = idx & 31;
    float v = ldf(nf, n, isf) * ldf(We, j, isf) + ldf(be, j, isf);
    x[idx] = lrelu(v);
}

// ---------------- graph offsets from sorted batch ----------------
__global__ void k_graph_off(const int* __restrict__ batch, int* __restrict__ goff, int N) {
    int n = blockIdx.x * 256 + threadIdx.x;
    if (n >= N) return;
    int bn = batch[n];
    if (n == 0) {
        for (int g = 0; g <= bn; ++g) goff[g] = 0;
    } else {
        int bp = batch[n - 1];
        for (int g = bp + 1; g <= bn; ++g) goff[g] = n;
    }
    if (n == N - 1) {
        for (int g = bn + 1; g <= GG; ++g) goff[g] = N;
    }
}

// ---------------- CSR build ----------------
__global__ void k_hist(const int* __restrict__ dst, unsigned* __restrict__ deg, int E) {
    int e = blockIdx.x * 256 + threadIdx.x;
    if (e >= E) return;
    atomicAdd(&deg[dst[e]], 1u);
}

__global__ void k_scan1(const unsigned* __restrict__ deg, unsigned* __restrict__ excl,
                        unsigned* __restrict__ bsum, int N) {
    __shared__ unsigned s[256];
    int i = blockIdx.x * 256 + threadIdx.x;
    unsigned v = (i < N) ? deg[i] : 0u;
    s[threadIdx.x] = v;
    __syncthreads();
    for (int off = 1; off < 256; off <<= 1) {
        unsigned t = (threadIdx.x >= (unsigned)off) ? s[threadIdx.x - off] : 0u;
        __syncthreads();
        s[threadIdx.x] += t;
        __syncthreads();
    }
    if (i < N) excl[i] = s[threadIdx.x] - v;
    if (threadIdx.x == 255) bsum[blockIdx.x] = s[255];
}

__global__ void k_scan2(const unsigned* __restrict__ bsum, unsigned* __restrict__ boff, int nb) {
    __shared__ unsigned s[256];
    __shared__ unsigned carry;
    if (threadIdx.x == 0) carry = 0u;
    __syncthreads();
    for (int base = 0; base < nb; base += 256) {
        int i = base + threadIdx.x;
        unsigned v = (i < nb) ? bsum[i] : 0u;
        s[threadIdx.x] = v;
        __syncthreads();
        for (int off = 1; off < 256; off <<= 1) {
            unsigned t = (threadIdx.x >= (unsigned)off) ? s[threadIdx.x - off] : 0u;
            __syncthreads();
            s[threadIdx.x] += t;
            __syncthreads();
        }
        if (i < nb) boff[i] = carry + s[threadIdx.x] - v;
        __syncthreads();
        if (threadIdx.x == 0) carry += s[255];
        __syncthreads();
    }
}

__global__ void k_scan3(unsigned* __restrict__ indptr, const unsigned* __restrict__ boff,
                        unsigned* __restrict__ cursor, int N, int E) {
    int i = blockIdx.x * 256 + threadIdx.x;
    if (i >= N) return;
    unsigned v = indptr[i] + boff[i >> 8];
    indptr[i] = v;
    cursor[i] = v;
    if (i == 0) indptr[N] = (unsigned)E;
}

__global__ void k_scatter(const int* __restrict__ src, const int* __restrict__ dst,
                          unsigned* __restrict__ cursor, unsigned* __restrict__ ssrc, int E) {
    int e = blockIdx.x * 256 + threadIdx.x;
    if (e >= E) return;
    unsigned pos = atomicAdd(&cursor[dst[e]], 1u);
    ssrc[pos] = (unsigned)src[e];
}

// ---------------- per-node message: m = bf16(lrelu(x @ Wm + bm)) ----------------
__global__ void k_msg(const float* __restrict__ x, const float* __restrict__ Wm,
                      const float* __restrict__ bm, __hip_bfloat16* __restrict__ m, int N) {
    __shared__ float WL[32 * 32];
    __shared__ float bL[32];
    __shared__ float xs[8][32];
    int tid = threadIdx.x;
    for (int t = tid; t < 1024; t += 256) WL[t] = Wm[t];
    if (tid < 32) bL[tid] = bm[tid];
    int s = tid >> 5, j = tid & 31;
    int n = blockIdx.x * 8 + s;
    if (n < N) xs[s][j] = x[n * 32 + j];
    __syncthreads();
    if (n >= N) return;
    float acc = bL[j];
#pragma unroll
    for (int k = 0; k < 32; ++k) acc += xs[s][k] * WL[k * 32 + j];
    m[n * 32 + j] = __float2bfloat16(lrelu(acc));
}

// ---------------- CSR segment-max ----------------
__global__ void k_aggmax(const unsigned* __restrict__ indptr, const unsigned* __restrict__ ssrc,
                         const __hip_bfloat16* __restrict__ m, float* __restrict__ agg, int N) {
    int tid = threadIdx.x;
    int s = tid >> 5, j = tid & 31;
    int n = blockIdx.x * 8 + s;
    if (n >= N) return;
    unsigned st = indptr[n], en = indptr[n + 1];
    float acc = -INFINITY;
    for (unsigned e = st; e < en; ++e) {
        unsigned sr = ssrc[e];
        acc = fmaxf(acc, b2f(m[sr * 32 + j]));
    }
    agg[n * 32 + j] = (en > st) ? acc : 0.f;
}

// ---------------- f_agg + gate logits ----------------
__global__ void k_fagg(float* __restrict__ x, const float* __restrict__ xg,
                       const float* __restrict__ agg, const int* __restrict__ batch,
                       const float* __restrict__ Wa, const float* __restrict__ ba,
                       const float* __restrict__ Wg, const float* __restrict__ bg,
                       float* __restrict__ logits, int N) {
    __shared__ float WL[96 * 32];
    __shared__ float zL[8][96];
    __shared__ float baL[32];
    __shared__ float WgL[32];
    __shared__ float bgL;
    int tid = threadIdx.x;
    for (int t = tid; t < 3072; t += 256) WL[t] = Wa[t];
    if (tid < 32) { baL[tid] = ba[tid]; WgL[tid] = Wg[tid]; }
    if (tid == 0) bgL = bg[0];
    int s = tid >> 5, j = tid & 31;
    int n = blockIdx.x * 8 + s;
    if (n < N) {
        zL[s][j] = x[n * 32 + j];
        int b = batch[n];
        zL[s][32 + j] = xg[b * 32 + j];
        zL[s][64 + j] = agg[n * 32 + j];
    }
    __syncthreads();
    if (n >= N) return;
    float acc = baL[j];
#pragma unroll
    for (int k = 0; k < 96; ++k) acc += zL[s][k] * WL[k * 32 + j];
    float xn = lrelu(acc) + zL[s][j];
    x[n * 32 + j] = xn;
    float lv = xn * WgL[j];
#pragma unroll
    for (int off = 16; off; off >>= 1) lv += __shfl_xor(lv, off);
    if (j == 0) logits[n] = lv + bgL;
}

// ---------------- per-graph pooling + xg update ----------------
__global__ void k_graph(const float* __restrict__ x, const float* __restrict__ logits,
                        const int* __restrict__ goff,
                        const float* __restrict__ Wf, const float* __restrict__ bf,
                        const float* __restrict__ Wt, const float* __restrict__ bt,
                        const float* __restrict__ xg_in, float* __restrict__ xg_out) {
    __shared__ float WfL[1024], bfL[32], WtL[2048], btL[32];
    __shared__ float red[256];
    __shared__ float xs[32][32];
    __shared__ float gv[32];
    __shared__ float pl[32];
    int g = blockIdx.x;
    int tid = threadIdx.x;
    for (int t = tid; t < 1024; t += 256) WfL[t] = Wf[t];
    for (int t = tid; t < 2048; t += 256) WtL[t] = Wt[t];
    if (tid < 32) { bfL[tid] = bf[tid]; btL[tid] = bt[tid]; }
    int s0 = goff[g], s1 = goff[g + 1];
    float lm = -INFINITY;
    for (int n = s0 + tid; n < s1; n += 256) lm = fmaxf(lm, logits[n]);
    red[tid] = lm;
    __syncthreads();
    for (int off = 128; off; off >>= 1) {
        if (tid < off) red[tid] = fmaxf(red[tid], red[tid + off]);
        __syncthreads();
    }
    float gmax = red[0];
    __syncthreads();
    float ls = 0.f;
    for (int n = s0 + tid; n < s1; n += 256) ls += expf(logits[n] - gmax);
    red[tid] = ls;
    __syncthreads();
    for (int off = 128; off; off >>= 1) {
        if (tid < off) red[tid] += red[tid + off];
        __syncthreads();
    }
    float inv = (red[0] > 0.f) ? 1.f / red[0] : 0.f;
    __syncthreads();
    int s = tid >> 5, j = tid & 31;
    float pacc = 0.f;
    for (int base = s0; base < s1; base += 32) {
        int cnt = min(32, s1 - base);
        for (int t = tid; t < 32 * 32; t += 256) {
            int r = t >> 5, c = t & 31;
            if (r < cnt) xs[r][c] = x[(base + r) * 32 + c];
        }
        if (tid < 32 && tid < cnt) gv[tid] = expf(logits[base + tid] - gmax) * inv;
        __syncthreads();
        for (int r = s; r < cnt; r += 8) {
            float f = bfL[j];
#pragma unroll
            for (int k = 0; k < 32; ++k) f += xs[r][k] * WfL[k * 32 + j];
            pacc += gv[r] * lrelu(f);
        }
        __syncthreads();
    }
    red[tid] = pacc;
    __syncthreads();
    if (tid < 32) {
        float p = 0.f;
#pragma unroll
        for (int r = 0; r < 8; ++r) p += red[r * 32 + tid];
        pl[tid] = p;
    }
    __syncthreads();
    if (tid < 32) {
        float acc = btL[tid];
#pragma unroll
        for (int k = 0; k < 32; ++k) acc += pl[k] * WtL[k * 32 + tid];
#pragma unroll
        for (int k = 0; k < 32; ++k) acc += xg_in[g * 32 + k] * WtL[(32 + k) * 32 + tid];
        xg_out[g * 32 + tid] = lrelu(acc) + xg_in[g * 32 + tid];
    }
}

// ---------------- a1 logits ----------------
__global__ void k_a1log(const float* __restrict__ x, const void* __restrict__ W,
                        const void* __restrict__ b, float* __restrict__ logits, int N,
                        const int* __restrict__ dtf) {
    __shared__ float WL[32];
    __shared__ float bL;
    int isf = *dtf;
    if (threadIdx.x < 32) WL[threadIdx.x] = ldf(W, threadIdx.x, isf);
    if (threadIdx.x == 0) bL = ldf(b, 0, isf);
    __syncthreads();
    int tid = threadIdx.x;
    int s = tid >> 5, j = tid & 31;
    int n = blockIdx.x * 8 + s;
    if (n >= N) return;
    float v = x[n * 32 + j] * WL[j];
#pragma unroll
    for (int off = 16; off; off >>= 1) v += __shfl_xor(v, off);
    if (j == 0) logits[n] = v + bL;
}

// ---------------- final: a1 softmax + value + a0 probs ----------------
__global__ void k_final(const float* __restrict__ logits, const int* __restrict__ goff,
                        const float* __restrict__ xg,
                        const void* __restrict__ Wv, const void* __restrict__ bv,
                        const void* __restrict__ Wa0, const void* __restrict__ ba0,
                        void* __restrict__ out, int N, const int* __restrict__ dtf) {
    __shared__ float red[256];
    int isf = *dtf;
    int g = blockIdx.x, tid = threadIdx.x;
    int s0 = goff[g], s1 = goff[g + 1];
    float lm = -INFINITY;
    for (int n = s0 + tid; n < s1; n += 256) lm = fmaxf(lm, logits[n]);
    red[tid] = lm;
    __syncthreads();
    for (int off = 128; off; off >>= 1) {
        if (tid < off) red[tid] = fmaxf(red[tid], red[tid + off]);
        __syncthreads();
    }
    float gmax = red[0];
    __syncthreads();
    float ls = 0.f;
    for (int n = s0 + tid; n < s1; n += 256) ls += expf(logits[n] - gmax);
    red[tid] = ls;
    __syncthreads();
    for (int off = 128; off; off >>= 1) {
        if (tid < off) red[tid] += red[tid + off];
        __syncthreads();
    }
    float inv = (red[0] > 0.f) ? 1.f / red[0] : 0.f;
    __syncthreads();
    for (int n = s0 + tid; n < s1; n += 256)
        stf(out, 384 + n, expf(logits[n] - gmax) * inv, isf);
    if (tid == 0) {
        float acc = ldf(bv, 0, isf);
        for (int k = 0; k < 32; ++k) acc += xg[g * 32 + k] * ldf(Wv, k, isf);
        stf(out, g, acc, isf);
        float l0 = ldf(ba0, 0, isf), l1 = ldf(ba0, 1, isf);
        for (int k = 0; k < 32; ++k) {
            float xv = xg[g * 32 + k];
            l0 += xv * ldf(Wa0, k * 2, isf);
            l1 += xv * ldf(Wa0, k * 2 + 1, isf);
        }
        float mm = fmaxf(l0, l1);
        float e0 = expf(l0 - mm), e1 = expf(l1 - mm);
        float si = 1.f / (e0 + e1);
        stf(out, 128 + 2 * g, e0 * si, isf);
        stf(out, 128 + 2 * g + 1, e1 * si, isf);
    }
}

extern "C" void kernel_launch(void* const* d_in, const int* in_sizes, int n_in,
                              void* d_out, int out_size, void* d_ws, size_t ws_size,
                              hipStream_t stream) {
    const void* nf      = d_in[0];
    const int*  eidx    = (const int*)d_in[1];
    const int*  batch   = (const int*)d_in[2];
    const void* W_embed = d_in[4];
    const void* b_embed = d_in[5];
    const void* Wm      = d_in[6];
    const void* bm      = d_in[7];
    const void* Wa      = d_in[8];
    const void* ba      = d_in[9];
    const void* Wgate   = d_in[10];
    const void* bgate   = d_in[11];
    const void* Wfeat   = d_in[12];
    const void* bfeat   = d_in[13];
    const void* Wt      = d_in[14];
    const void* bt      = d_in[15];
    const void* W_v     = d_in[16];
    const void* b_v     = d_in[17];
    const void* W_a0    = d_in[18];
    const void* b_a0    = d_in[19];
    const void* W_a1    = d_in[20];
    const void* b_a1    = d_in[21];

    const int N = in_sizes[0];
    const int E = in_sizes[1] / 2;
    const int nWm = in_sizes[6];  // 3*32*32 = 3072
    const int* src = eidx;
    const int* dst = eidx + E;

    char* ws = (char*)d_ws;
    size_t off = 0;
    auto alloc = [&](size_t bytes) -> char* {
        char* p = ws + off;
        off = (off + bytes + 255) & ~(size_t)255;
        return p;
    };
    float*          x      = (float*)alloc((size_t)N * 32 * 4);
    float*          agg    = (float*)alloc((size_t)N * 32 * 4);
    __hip_bfloat16* m      = (__hip_bfloat16*)alloc((size_t)N * 32 * 2);
    float*          logits = (float*)alloc((size_t)N * 4);
    unsigned*       indptr = (unsigned*)alloc((size_t)(N + 1) * 4);
    unsigned*       cursor = (unsigned*)alloc((size_t)N * 4);
    unsigned*       ssrc   = (unsigned*)alloc((size_t)E * 4);
    const int nb = (N + 255) / 256;
    unsigned*       bsum   = (unsigned*)alloc((size_t)nb * 4);
    unsigned*       boff   = (unsigned*)alloc((size_t)nb * 4);
    int*            goff   = (int*)alloc((size_t)(GG + 1) * 4);
    float*          xg_a   = (float*)alloc((size_t)GG * 32 * 4);
    float*          xg_b   = (float*)alloc((size_t)GG * 32 * 4);
    int*            dtf    = (int*)alloc(256);
    float*          Wm_f   = (float*)alloc((size_t)3 * 1024 * 4);
    float*          bm_f   = (float*)alloc((size_t)3 * 32 * 4);
    float*          Wa_f   = (float*)alloc((size_t)3 * 3072 * 4);
    float*          ba_f   = (float*)alloc((size_t)3 * 32 * 4);
    float*          Wg_f   = (float*)alloc((size_t)3 * 32 * 4);
    float*          bg_f   = (float*)alloc((size_t)3 * 4);
    float*          Wf_f   = (float*)alloc((size_t)3 * 1024 * 4);
    float*          bf_f   = (float*)alloc((size_t)3 * 32 * 4);
    float*          Wt_f   = (float*)alloc((size_t)3 * 2048 * 4);
    float*          bt_f   = (float*)alloc((size_t)3 * 32 * 4);

    const int nB_n  = (N + 255) / 256;
    const int nB_e  = (E + 255) / 256;
    const int nB_n8 = (N + 7) / 8;
    const int nB_nj = (N * 32 + 255) / 256;

    hipMemsetAsync(cursor, 0, (size_t)N * 4, stream);
    hipMemsetAsync(xg_a, 0, (size_t)GG * 32 * 4, stream);

    k_detect<<<1, 256, 0, stream>>>((const unsigned short*)Wm, nWm, dtf);

    // stage all stepped weights as f32 (dtype-agnostic afterwards)
    k_cvt<<<(3 * 1024 + 255) / 256, 256, 0, stream>>>(Wm, Wm_f, 3 * 1024, dtf);
    k_cvt<<<1, 256, 0, stream>>>(bm, bm_f, 3 * 32, dtf);
    k_cvt<<<(3 * 3072 + 255) / 256, 256, 0, stream>>>(Wa, Wa_f, 3 * 3072, dtf);
    k_cvt<<<1, 256, 0, stream>>>(ba, ba_f, 3 * 32, dtf);
    k_cvt<<<1, 256, 0, stream>>>(Wgate, Wg_f, 3 * 32, dtf);
    k_cvt<<<1, 256, 0, stream>>>(bgate, bg_f, 3, dtf);
    k_cvt<<<(3 * 1024 + 255) / 256, 256, 0, stream>>>(Wfeat, Wf_f, 3 * 1024, dtf);
    k_cvt<<<1, 256, 0, stream>>>(bfeat, bf_f, 3 * 32, dtf);
    k_cvt<<<(3 * 2048 + 255) / 256, 256, 0, stream>>>(Wt, Wt_f, 3 * 2048, dtf);
    k_cvt<<<1, 256, 0, stream>>>(bt, bt_f, 3 * 32, dtf);

    k_embed<<<nB_nj, 256, 0, stream>>>(nf, W_embed, b_embed, x, N, dtf);
    k_graph_off<<<nB_n, 256, 0, stream>>>(batch, goff, N);

    k_hist<<<nB_e, 256, 0, stream>>>(dst, cursor, E);
    k_scan1<<<nb, 256, 0, stream>>>(cursor, indptr, bsum, N);
    k_scan2<<<1, 256, 0, stream>>>(bsum, boff, nb);
    k_scan3<<<nB_n, 256, 0, stream>>>(indptr, boff, cursor, N, E);
    k_scatter<<<nB_e, 256, 0, stream>>>(src, dst, cursor, ssrc, E);

    float* xg_cur = xg_a;
    float* xg_nxt = xg_b;
    for (int i = 0; i < 3; ++i) {
        k_msg<<<nB_n8, 256, 0, stream>>>(x, Wm_f + i * 1024, bm_f + i * 32, m, N);
        k_aggmax<<<nB_n8, 256, 0, stream>>>(indptr, ssrc, m, agg, N);
        k_fagg<<<nB_n8, 256, 0, stream>>>(x, xg_cur, agg, batch,
                                          Wa_f + i * 3072, ba_f + i * 32,
                                          Wg_f + i * 32, bg_f + i, logits, N);
        k_graph<<<GG, 256, 0, stream>>>(x, logits, goff,
                                        Wf_f + i * 1024, bf_f + i * 32,
                                        Wt_f + i * 2048, bt_f + i * 32,
                                        xg_cur, xg_nxt);
        float* tmp = xg_cur; xg_cur = xg_nxt; xg_nxt = tmp;
    }

    k_a1log<<<nB_n8, 256, 0, stream>>>(x, W_a1, b_a1, logits, N, dtf);
    k_final<<<GG, 256, 0, stream>>>(logits, goff, xg_cur, W_v, b_v, W_a0, b_a0,
                                    d_out, N, dtf);
}

// Round 3
// 1403.869 us; speedup vs baseline: 1.1316x; 1.1316x over previous
//
#include <hip/hip_runtime.h>
#include <hip/hip_bf16.h>

#define GG 128
#define SLOPE 0.01f

__device__ __forceinline__ float lrelu(float v) { return v > 0.f ? v : SLOPE * v; }
__device__ __forceinline__ float b2f(__hip_bfloat16 v) { return __bfloat162float(v); }

// dtype-flexible load/store: isf=1 -> buffer holds f32, isf=0 -> bf16
__device__ __forceinline__ float ldf(const void* p, int i, int isf) {
    if (isf) return ((const float*)p)[i];
    return __bfloat162float(((const __hip_bfloat16*)p)[i]);
}
__device__ __forceinline__ void stf(void* p, int i, float v, int isf) {
    if (isf) ((float*)p)[i] = v;
    else ((__hip_bfloat16*)p)[i] = __float2bfloat16(v);
}

// ---------------- dtype detection ----------------
__global__ void k_detect(const unsigned short* __restrict__ w, int n, int* __restrict__ flag) {
    __shared__ int bad;
    if (threadIdx.x == 0) bad = 0;
    __syncthreads();
    for (int t = threadIdx.x; t < n; t += 256) {
        unsigned short u = w[t];
        int e = (u >> 7) & 0xFF;
        if (e >= 141) bad = 1;  // benign same-value race
    }
    __syncthreads();
    if (threadIdx.x == 0) { flag[0] = bad; flag[32] = 1; }
}

// generic elementwise convert (possibly-bf16/possibly-f32 -> f32)
__global__ void k_cvt(const void* __restrict__ src, float* __restrict__ dst, int n,
                      const int* __restrict__ dtf) {
    int isf = *dtf;
    int i = blockIdx.x * 256 + threadIdx.x;
    if (i < n) dst[i] = ldf(src, i, isf);
}

// ---------------- embed ----------------
__global__ void k_embed(const void* __restrict__ nf, const void* __restrict__ We,
                        const void* __restrict__ be, float* __restrict__ x, int N,
                        const int* __restrict__ dtf) {
    int isf = *dtf;
    int idx = blockIdx.x * 256 + threadIdx.x;
    if (idx >= N * 32) return;
    int n = idx >> 5, j = idx & 31;
    float v = ldf(nf, n, isf) * ldf(We, j, isf) + ldf(be, j, isf);
    x[idx] = lrelu(v);
}

// ---------------- graph offsets from sorted batch ----------------
__global__ void k_graph_off(const int* __restrict__ batch, int* __restrict__ goff, int N) {
    int n = blockIdx.x * 256 + threadIdx.x;
    if (n >= N) return;
    int bn = batch[n];
    if (n == 0) {
        for (int g = 0; g <= bn; ++g) goff[g] = 0;
    } else {
        int bp = batch[n - 1];
        for (int g = bp + 1; g <= bn; ++g) goff[g] = n;
    }
    if (n == N - 1) {
        for (int g = bn + 1; g <= GG; ++g) goff[g] = N;
    }
}

// ---------------- CSR build: node-degree histogram + scans ----------------
__global__ void k_hist(const int* __restrict__ dst, unsigned* __restrict__ deg, int E) {
    int e = blockIdx.x * 256 + threadIdx.x;
    if (e >= E) return;
    atomicAdd(&deg[dst[e]], 1u);
}

__global__ void k_scan1(const unsigned* __restrict__ deg, unsigned* __restrict__ excl,
                        unsigned* __restrict__ bsum, int N) {
    __shared__ unsigned s[256];
    int i = blockIdx.x * 256 + threadIdx.x;
    unsigned v = (i < N) ? deg[i] : 0u;
    s[threadIdx.x] = v;
    __syncthreads();
    for (int off = 1; off < 256; off <<= 1) {
        unsigned t = (threadIdx.x >= (unsigned)off) ? s[threadIdx.x - off] : 0u;
        __syncthreads();
        s[threadIdx.x] += t;
        __syncthreads();
    }
    if (i < N) excl[i] = s[threadIdx.x] - v;
    if (threadIdx.x == 255) bsum[blockIdx.x] = s[255];
}

__global__ void k_scan2(const unsigned* __restrict__ bsum, unsigned* __restrict__ boff, int nb) {
    __shared__ unsigned s[256];
    __shared__ unsigned carry;
    if (threadIdx.x == 0) carry = 0u;
    __syncthreads();
    for (int base = 0; base < nb; base += 256) {
        int i = base + threadIdx.x;
        unsigned v = (i < nb) ? bsum[i] : 0u;
        s[threadIdx.x] = v;
        __syncthreads();
        for (int off = 1; off < 256; off <<= 1) {
            unsigned t = (threadIdx.x >= (unsigned)off) ? s[threadIdx.x - off] : 0u;
            __syncthreads();
            s[threadIdx.x] += t;
            __syncthreads();
        }
        if (i < nb) boff[i] = carry + s[threadIdx.x] - v;
        __syncthreads();
        if (threadIdx.x == 0) carry += s[255];
        __syncthreads();
    }
}

__global__ void k_scan3(unsigned* __restrict__ indptr, const unsigned* __restrict__ boff,
                        unsigned* __restrict__ cursor, int N, int E) {
    int i = blockIdx.x * 256 + threadIdx.x;
    if (i >= N) return;
    unsigned v = indptr[i] + boff[i >> 8];
    indptr[i] = v;
    cursor[i] = v;
    if (i == 0) indptr[N] = (unsigned)E;
}

// ---------------- fallback scatter (only if B > 2048) ----------------
__global__ void k_scatter(const int* __restrict__ src, const int* __restrict__ dst,
                          unsigned* __restrict__ cursor, unsigned* __restrict__ ssrc, int E) {
    int e = blockIdx.x * 256 + threadIdx.x;
    if (e >= E) return;
    unsigned pos = atomicAdd(&cursor[dst[e]], 1u);
    ssrc[pos] = (unsigned)src[e];
}

// ---------------- bucketed scatter: phase bucket-histogram ----------------
// bucket = dst >> 8 (256 nodes per bucket), B <= 2048
#define CHUNK 8192
__global__ void k_bhist(const int* __restrict__ dst, unsigned* __restrict__ bcnt, int E, int B) {
    __shared__ unsigned h[2048];
    for (int t = threadIdx.x; t < B; t += 256) h[t] = 0;
    __syncthreads();
    int start = blockIdx.x * CHUNK, end = min(E, start + CHUNK);
    for (int e = start + threadIdx.x; e < end; e += 256)
        atomicAdd(&h[dst[e] >> 8], 1u);
    __syncthreads();
    for (int t = threadIdx.x; t < B; t += 256)
        if (h[t]) atomicAdd(&bcnt[t], h[t]);
}

// exclusive scan of bcnt -> bbase (and bcur copy); bbase[B] = E
__global__ void k_bscan(const unsigned* __restrict__ bcnt, unsigned* __restrict__ bbase,
                        unsigned* __restrict__ bcur, int B, int E) {
    __shared__ unsigned s[256];
    __shared__ unsigned carry;
    if (threadIdx.x == 0) carry = 0u;
    __syncthreads();
    for (int base = 0; base < B; base += 256) {
        int i = base + threadIdx.x;
        unsigned v = (i < B) ? bcnt[i] : 0u;
        s[threadIdx.x] = v;
        __syncthreads();
        for (int off = 1; off < 256; off <<= 1) {
            unsigned t = (threadIdx.x >= (unsigned)off) ? s[threadIdx.x - off] : 0u;
            __syncthreads();
            s[threadIdx.x] += t;
            __syncthreads();
        }
        if (i < B) {
            unsigned ex = carry + s[threadIdx.x] - v;
            bbase[i] = ex;
            bcur[i] = ex;
        }
        __syncthreads();
        if (threadIdx.x == 0) carry += s[255];
        __syncthreads();
    }
    if (threadIdx.x == 0) bbase[B] = (unsigned)E;
}

// bin edges into bucket-contiguous packed (dst,src) u64 array
__global__ void k_binA(const int* __restrict__ src, const int* __restrict__ dst,
                       unsigned* __restrict__ bcur, unsigned long long* __restrict__ packed,
                       int E, int B) {
    __shared__ unsigned h[2048];
    __shared__ unsigned pos[2048];
    for (int t = threadIdx.x; t < B; t += 256) h[t] = 0;
    __syncthreads();
    int start = blockIdx.x * CHUNK, end = min(E, start + CHUNK);
    for (int e = start + threadIdx.x; e < end; e += 256)
        atomicAdd(&h[dst[e] >> 8], 1u);
    __syncthreads();
    for (int t = threadIdx.x; t < B; t += 256)
        pos[t] = h[t] ? atomicAdd(&bcur[t], h[t]) : 0u;
    __syncthreads();
    for (int e = start + threadIdx.x; e < end; e += 256) {
        int d = dst[e];
        unsigned p = atomicAdd(&pos[d >> 8], 1u);
        packed[p] = ((unsigned long long)(unsigned)d << 32) | (unsigned)src[e];
    }
}

// per-bucket scatter into final CSR order: output window ~16KB -> L2-local
__global__ void k_scatterB(const unsigned long long* __restrict__ packed,
                           const unsigned* __restrict__ bbase,
                           const unsigned* __restrict__ indptr,
                           unsigned* __restrict__ ssrc, int N) {
    __shared__ unsigned cur[256];
    int g = blockIdx.x;
    int n0 = g << 8;
    int cnt = min(256, N - n0);
    if ((int)threadIdx.x < cnt) cur[threadIdx.x] = indptr[n0 + threadIdx.x];
    __syncthreads();
    unsigned e0 = bbase[g], e1 = bbase[g + 1];
    for (unsigned e = e0 + threadIdx.x; e < e1; e += 256) {
        unsigned long long pk = packed[e];
        int d = (int)(pk >> 32);
        unsigned s = (unsigned)pk;
        unsigned p = atomicAdd(&cur[d - n0], 1u);
        ssrc[p] = s;
    }
}

// ---------------- per-node message ----------------
__global__ void k_msg(const float* __restrict__ x, const float* __restrict__ Wm,
                      const float* __restrict__ bm, __hip_bfloat16* __restrict__ m, int N) {
    __shared__ float WL[32 * 32];
    __shared__ float bL[32];
    __shared__ float xs[8][32];
    int tid = threadIdx.x;
    for (int t = tid; t < 1024; t += 256) WL[t] = Wm[t];
    if (tid < 32) bL[tid] = bm[tid];
    int s = tid >> 5, j = tid & 31;
    int n = blockIdx.x * 8 + s;
    if (n < N) xs[s][j] = x[n * 32 + j];
    __syncthreads();
    if (n >= N) return;
    float acc = bL[j];
#pragma unroll
    for (int k = 0; k < 32; ++k) acc += xs[s][k] * WL[k * 32 + j];
    m[n * 32 + j] = __float2bfloat16(lrelu(acc));
}

// ---------------- CSR segment-max ----------------
__global__ void k_aggmax(const unsigned* __restrict__ indptr, const unsigned* __restrict__ ssrc,
                         const __hip_bfloat16* __restrict__ m, float* __restrict__ agg, int N) {
    int tid = threadIdx.x;
    int s = tid >> 5, j = tid & 31;
    int n = blockIdx.x * 8 + s;
    if (n >= N) return;
    unsigned st = indptr[n], en = indptr[n + 1];
    float acc = -INFINITY;
    for (unsigned e = st; e < en; ++e) {
        unsigned sr = ssrc[e];
        acc = fmaxf(acc, b2f(m[sr * 32 + j]));
    }
    agg[n * 32 + j] = (en > st) ? acc : 0.f;
}

// ---------------- f_agg + gate logits ----------------
__global__ void k_fagg(float* __restrict__ x, const float* __restrict__ xg,
                       const float* __restrict__ agg, const int* __restrict__ batch,
                       const float* __restrict__ Wa, const float* __restrict__ ba,
                       const float* __restrict__ Wg, const float* __restrict__ bg,
                       float* __restrict__ logits, int N) {
    __shared__ float WL[96 * 32];
    __shared__ float zL[8][96];
    __shared__ float baL[32];
    __shared__ float WgL[32];
    __shared__ float bgL;
    int tid = threadIdx.x;
    for (int t = tid; t < 3072; t += 256) WL[t] = Wa[t];
    if (tid < 32) { baL[tid] = ba[tid]; WgL[tid] = Wg[tid]; }
    if (tid == 0) bgL = bg[0];
    int s = tid >> 5, j = tid & 31;
    int n = blockIdx.x * 8 + s;
    if (n < N) {
        zL[s][j] = x[n * 32 + j];
        int b = batch[n];
        zL[s][32 + j] = xg[b * 32 + j];
        zL[s][64 + j] = agg[n * 32 + j];
    }
    __syncthreads();
    if (n >= N) return;
    float acc = baL[j];
#pragma unroll
    for (int k = 0; k < 96; ++k) acc += zL[s][k] * WL[k * 32 + j];
    float xn = lrelu(acc) + zL[s][j];
    x[n * 32 + j] = xn;
    float lv = xn * WgL[j];
#pragma unroll
    for (int off = 16; off; off >>= 1) lv += __shfl_xor(lv, off);
    if (j == 0) logits[n] = lv + bgL;
}

// ---------------- per-graph pooling + xg update ----------------
__global__ void k_graph(const float* __restrict__ x, const float* __restrict__ logits,
                        const int* __restrict__ goff,
                        const float* __restrict__ Wf, const float* __restrict__ bf,
                        const float* __restrict__ Wt, const float* __restrict__ bt,
                        const float* __restrict__ xg_in, float* __restrict__ xg_out) {
    __shared__ float WfL[1024], bfL[32], WtL[2048], btL[32];
    __shared__ float red[256];
    __shared__ float xs[32][32];
    __shared__ float gv[32];
    __shared__ float pl[32];
    int g = blockIdx.x;
    int tid = threadIdx.x;
    for (int t = tid; t < 1024; t += 256) WfL[t] = Wf[t];
    for (int t = tid; t < 2048; t += 256) WtL[t] = Wt[t];
    if (tid < 32) { bfL[tid] = bf[tid]; btL[tid] = bt[tid]; }
    int s0 = goff[g], s1 = goff[g + 1];
    float lm = -INFINITY;
    for (int n = s0 + tid; n < s1; n += 256) lm = fmaxf(lm, logits[n]);
    red[tid] = lm;
    __syncthreads();
    for (int off = 128; off; off >>= 1) {
        if (tid < off) red[tid] = fmaxf(red[tid], red[tid + off]);
        __syncthreads();
    }
    float gmax = red[0];
    __syncthreads();
    float ls = 0.f;
    for (int n = s0 + tid; n < s1; n += 256) ls += expf(logits[n] - gmax);
    red[tid] = ls;
    __syncthreads();
    for (int off = 128; off; off >>= 1) {
        if (tid < off) red[tid] += red[tid + off];
        __syncthreads();
    }
    float inv = (red[0] > 0.f) ? 1.f / red[0] : 0.f;
    __syncthreads();
    int s = tid >> 5, j = tid & 31;
    float pacc = 0.f;
    for (int base = s0; base < s1; base += 32) {
        int cnt = min(32, s1 - base);
        for (int t = tid; t < 32 * 32; t += 256) {
            int r = t >> 5, c = t & 31;
            if (r < cnt) xs[r][c] = x[(base + r) * 32 + c];
        }
        if (tid < 32 && tid < cnt) gv[tid] = expf(logits[base + tid] - gmax) * inv;
        __syncthreads();
        for (int r = s; r < cnt; r += 8) {
            float f = bfL[j];
#pragma unroll
            for (int k = 0; k < 32; ++k) f += xs[r][k] * WfL[k * 32 + j];
            pacc += gv[r] * lrelu(f);
        }
        __syncthreads();
    }
    red[tid] = pacc;
    __syncthreads();
    if (tid < 32) {
        float p = 0.f;
#pragma unroll
        for (int r = 0; r < 8; ++r) p += red[r * 32 + tid];
        pl[tid] = p;
    }
    __syncthreads();
    if (tid < 32) {
        float acc = btL[tid];
#pragma unroll
        for (int k = 0; k < 32; ++k) acc += pl[k] * WtL[k * 32 + tid];
#pragma unroll
        for (int k = 0; k < 32; ++k) acc += xg_in[g * 32 + k] * WtL[(32 + k) * 32 + tid];
        xg_out[g * 32 + tid] = lrelu(acc) + xg_in[g * 32 + tid];
    }
}

// ---------------- a1 logits ----------------
__global__ void k_a1log(const float* __restrict__ x, const void* __restrict__ W,
                        const void* __restrict__ b, float* __restrict__ logits, int N,
                        const int* __restrict__ dtf) {
    __shared__ float WL[32];
    __shared__ float bL;
    int isf = *dtf;
    if (threadIdx.x < 32) WL[threadIdx.x] = ldf(W, threadIdx.x, isf);
    if (threadIdx.x == 0) bL = ldf(b, 0, isf);
    __syncthreads();
    int tid = threadIdx.x;
    int s = tid >> 5, j = tid & 31;
    int n = blockIdx.x * 8 + s;
    if (n >= N) return;
    float v = x[n * 32 + j] * WL[j];
#pragma unroll
    for (int off = 16; off; off >>= 1) v += __shfl_xor(v, off);
    if (j == 0) logits[n] = v + bL;
}

// ---------------- final: a1 softmax + value + a0 probs ----------------
__global__ void k_final(const float* __restrict__ logits, const int* __restrict__ goff,
                        const float* __restrict__ xg,
                        const void* __restrict__ Wv, const void* __restrict__ bv,
                        const void* __restrict__ Wa0, const void* __restrict__ ba0,
                        void* __restrict__ out, int N, const int* __restrict__ dtf) {
    __shared__ float red[256];
    int isf = *dtf;
    int g = blockIdx.x, tid = threadIdx.x;
    int s0 = goff[g], s1 = goff[g + 1];
    float lm = -INFINITY;
    for (int n = s0 + tid; n < s1; n += 256) lm = fmaxf(lm, logits[n]);
    red[tid] = lm;
    __syncthreads();
    for (int off = 128; off; off >>= 1) {
        if (tid < off) red[tid] = fmaxf(red[tid], red[tid + off]);
        __syncthreads();
    }
    float gmax = red[0];
    __syncthreads();
    float ls = 0.f;
    for (int n = s0 + tid; n < s1; n += 256) ls += expf(logits[n] - gmax);
    red[tid] = ls;
    __syncthreads();
    for (int off = 128; off; off >>= 1) {
        if (tid < off) red[tid] += red[tid + off];
        __syncthreads();
    }
    float inv = (red[0] > 0.f) ? 1.f / red[0] : 0.f;
    __syncthreads();
    for (int n = s0 + tid; n < s1; n += 256)
        stf(out, 384 + n, expf(logits[n] - gmax) * inv, isf);
    if (tid == 0) {
        float acc = ldf(bv, 0, isf);
        for (int k = 0; k < 32; ++k) acc += xg[g * 32 + k] * ldf(Wv, k, isf);
        stf(out, g, acc, isf);
        float l0 = ldf(ba0, 0, isf), l1 = ldf(ba0, 1, isf);
        for (int k = 0; k < 32; ++k) {
            float xv = xg[g * 32 + k];
            l0 += xv * ldf(Wa0, k * 2, isf);
            l1 += xv * ldf(Wa0, k * 2 + 1, isf);
        }
        float mm = fmaxf(l0, l1);
        float e0 = expf(l0 - mm), e1 = expf(l1 - mm);
        float si = 1.f / (e0 + e1);
        stf(out, 128 + 2 * g, e0 * si, isf);
        stf(out, 128 + 2 * g + 1, e1 * si, isf);
    }
}

extern "C" void kernel_launch(void* const* d_in, const int* in_sizes, int n_in,
                              void* d_out, int out_size, void* d_ws, size_t ws_size,
                              hipStream_t stream) {
    const void* nf      = d_in[0];
    const int*  eidx    = (const int*)d_in[1];
    const int*  batch   = (const int*)d_in[2];
    const void* W_embed = d_in[4];
    const void* b_embed = d_in[5];
    const void* Wm      = d_in[6];
    const void* bm      = d_in[7];
    const void* Wa      = d_in[8];
    const void* ba      = d_in[9];
    const void* Wgate   = d_in[10];
    const void* bgate   = d_in[11];
    const void* Wfeat   = d_in[12];
    const void* bfeat   = d_in[13];
    const void* Wt      = d_in[14];
    const void* bt      = d_in[15];
    const void* W_v     = d_in[16];
    const void* b_v     = d_in[17];
    const void* W_a0    = d_in[18];
    const void* b_a0    = d_in[19];
    const void* W_a1    = d_in[20];
    const void* b_a1    = d_in[21];

    const int N = in_sizes[0];
    const int E = in_sizes[1] / 2;
    const int nWm = in_sizes[6];  // 3*32*32 = 3072
    const int* src = eidx;
    const int* dst = eidx + E;
    const int B = (N + 255) >> 8;  // nodes/bucket = 256

    char* ws = (char*)d_ws;
    size_t off = 0;
    auto alloc = [&](size_t bytes) -> char* {
        char* p = ws + off;
        off = (off + bytes + 255) & ~(size_t)255;
        return p;
    };
    float*          x      = (float*)alloc((size_t)N * 32 * 4);
    // agg (N*32*4 B) aliases packed (E*8 B): packed is dead before agg's first write
    size_t aggBytes = (size_t)N * 32 * 4;
    size_t pkBytes  = (size_t)E * 8;
    char*  aggRegion = alloc(aggBytes > pkBytes ? aggBytes : pkBytes);
    float*              agg    = (float*)aggRegion;
    unsigned long long* packed = (unsigned long long*)aggRegion;
    __hip_bfloat16* m      = (__hip_bfloat16*)alloc((size_t)N * 32 * 2);
    float*          logits = (float*)alloc((size_t)N * 4);
    unsigned*       indptr = (unsigned*)alloc((size_t)(N + 1) * 4);
    unsigned*       cursor = (unsigned*)alloc((size_t)N * 4);
    unsigned*       ssrc   = (unsigned*)alloc((size_t)E * 4);
    const int nb = (N + 255) / 256;
    unsigned*       bsum   = (unsigned*)alloc((size_t)nb * 4);
    unsigned*       boff   = (unsigned*)alloc((size_t)nb * 4);
    unsigned*       bcnt   = (unsigned*)alloc((size_t)(B + 1) * 4);
    unsigned*       bbase  = (unsigned*)alloc((size_t)(B + 1) * 4);
    unsigned*       bcur   = (unsigned*)alloc((size_t)(B + 1) * 4);
    int*            goff   = (int*)alloc((size_t)(GG + 1) * 4);
    float*          xg_a   = (float*)alloc((size_t)GG * 32 * 4);
    float*          xg_b   = (float*)alloc((size_t)GG * 32 * 4);
    int*            dtf    = (int*)alloc(256);
    float*          Wm_f   = (float*)alloc((size_t)3 * 1024 * 4);
    float*          bm_f   = (float*)alloc((size_t)3 * 32 * 4);
    float*          Wa_f   = (float*)alloc((size_t)3 * 3072 * 4);
    float*          ba_f   = (float*)alloc((size_t)3 * 32 * 4);
    float*          Wg_f   = (float*)alloc((size_t)3 * 32 * 4);
    float*          bg_f   = (float*)alloc((size_t)3 * 4);
    float*          Wf_f   = (float*)alloc((size_t)3 * 1024 * 4);
    float*          bf_f   = (float*)alloc((size_t)3 * 32 * 4);
    float*          Wt_f   = (float*)alloc((size_t)3 * 2048 * 4);
    float*          bt_f   = (float*)alloc((size_t)3 * 32 * 4);

    const int nB_n  = (N + 255) / 256;
    const int nB_e  = (E + 255) / 256;
    const int nB_n8 = (N + 7) / 8;
    const int nB_nj = (N * 32 + 255) / 256;
    const int nB_ch = (E + CHUNK - 1) / CHUNK;

    hipMemsetAsync(cursor, 0, (size_t)N * 4, stream);
    hipMemsetAsync(xg_a, 0, (size_t)GG * 32 * 4, stream);
    hipMemsetAsync(bcnt, 0, (size_t)(B + 1) * 4, stream);

    k_detect<<<1, 256, 0, stream>>>((const unsigned short*)Wm, nWm, dtf);

    // stage all stepped weights as f32
    k_cvt<<<(3 * 1024 + 255) / 256, 256, 0, stream>>>(Wm, Wm_f, 3 * 1024, dtf);
    k_cvt<<<1, 256, 0, stream>>>(bm, bm_f, 3 * 32, dtf);
    k_cvt<<<(3 * 3072 + 255) / 256, 256, 0, stream>>>(Wa, Wa_f, 3 * 3072, dtf);
    k_cvt<<<1, 256, 0, stream>>>(ba, ba_f, 3 * 32, dtf);
    k_cvt<<<1, 256, 0, stream>>>(Wgate, Wg_f, 3 * 32, dtf);
    k_cvt<<<1, 256, 0, stream>>>(bgate, bg_f, 3, dtf);
    k_cvt<<<(3 * 1024 + 255) / 256, 256, 0, stream>>>(Wfeat, Wf_f, 3 * 1024, dtf);
    k_cvt<<<1, 256, 0, stream>>>(bfeat, bf_f, 3 * 32, dtf);
    k_cvt<<<(3 * 2048 + 255) / 256, 256, 0, stream>>>(Wt, Wt_f, 3 * 2048, dtf);
    k_cvt<<<1, 256, 0, stream>>>(bt, bt_f, 3 * 32, dtf);

    k_embed<<<nB_nj, 256, 0, stream>>>(nf, W_embed, b_embed, x, N, dtf);
    k_graph_off<<<nB_n, 256, 0, stream>>>(batch, goff, N);

    // node-degree histogram + scan -> indptr
    k_hist<<<nB_e, 256, 0, stream>>>(dst, cursor, E);
    k_scan1<<<nb, 256, 0, stream>>>(cursor, indptr, bsum, N);
    k_scan2<<<1, 256, 0, stream>>>(bsum, boff, nb);
    k_scan3<<<nB_n, 256, 0, stream>>>(indptr, boff, cursor, N, E);

    if (B <= 2048) {
        // bucketed scatter: bucket-local output windows -> L2 write combining
        k_bhist<<<nB_ch, 256, 0, stream>>>(dst, bcnt, E, B);
        k_bscan<<<1, 256, 0, stream>>>(bcnt, bbase, bcur, B, E);
        k_binA<<<nB_ch, 256, 0, stream>>>(src, dst, bcur, packed, E, B);
        k_scatterB<<<B, 256, 0, stream>>>(packed, bbase, indptr, ssrc, N);
    } else {
        k_scatter<<<nB_e, 256, 0, stream>>>(src, dst, cursor, ssrc, E);
    }

    float* xg_cur = xg_a;
    float* xg_nxt = xg_b;
    for (int i = 0; i < 3; ++i) {
        k_msg<<<nB_n8, 256, 0, stream>>>(x, Wm_f + i * 1024, bm_f + i * 32, m, N);
        k_aggmax<<<nB_n8, 256, 0, stream>>>(indptr, ssrc, m, agg, N);
        k_fagg<<<nB_n8, 256, 0, stream>>>(x, xg_cur, agg, batch,
                                          Wa_f + i * 3072, ba_f + i * 32,
                                          Wg_f + i * 32, bg_f + i, logits, N);
        k_graph<<<GG, 256, 0, stream>>>(x, logits, goff,
                                        Wf_f + i * 1024, bf_f + i * 32,
                                        Wt_f + i * 2048, bt_f + i * 32,
                                        xg_cur, xg_nxt);
        float* tmp = xg_cur; xg_cur = xg_nxt; xg_nxt = tmp;
    }

    k_a1log<<<nB_n8, 256, 0, stream>>>(x, W_a1, b_a1, logits, N, dtf);
    k_final<<<GG, 256, 0, stream>>>(logits, goff, xg_cur, W_v, b_v, W_a0, b_a0,
                                    d_out, N, dtf);
}

// Round 4
// 1136.004 us; speedup vs baseline: 1.3984x; 1.2358x over previous
//
#include <hip/hip_runtime.h>
#include <hip/hip_bf16.h>

#define GG 128
#define SLOPE 0.01f
#define CHUNK 8192

// wcat element offsets (f32 staged weights)
#define OFF_Wm   0
#define OFF_bm   3072
#define OFF_Wa   3168
#define OFF_ba   12384
#define OFF_Wg   12480
#define OFF_bg   12576
#define OFF_Wf   12592
#define OFF_bf   15664
#define OFF_Wt   15760
#define OFF_bt   21904
#define OFF_Wa1  22000
#define OFF_ba1  22032
#define WCAT_N   22048

__device__ __forceinline__ float lrelu(float v) { return v > 0.f ? v : SLOPE * v; }
__device__ __forceinline__ float b2f(__hip_bfloat16 v) { return __bfloat162float(v); }

__device__ __forceinline__ float ldf(const void* p, int i, int isf) {
    if (isf) return ((const float*)p)[i];
    return __bfloat162float(((const __hip_bfloat16*)p)[i]);
}
__device__ __forceinline__ void stf(void* p, int i, float v, int isf) {
    if (isf) ((float*)p)[i] = v;
    else ((__hip_bfloat16*)p)[i] = __float2bfloat16(v);
}

// ---------------- dtype detection ----------------
__global__ void k_detect(const unsigned short* __restrict__ w, int n, int* __restrict__ flag) {
    __shared__ int bad;
    if (threadIdx.x == 0) bad = 0;
    __syncthreads();
    for (int t = threadIdx.x; t < n; t += 256) {
        unsigned short u = w[t];
        int e = (u >> 7) & 0xFF;
        if (e >= 141) bad = 1;  // benign same-value race
    }
    __syncthreads();
    if (threadIdx.x == 0) { flag[0] = bad; flag[32] = 1; }
}

// ---------------- one-shot weight staging to f32 ----------------
struct CvtArgs {
    const void* p[12];
    int off[12];
    int n[12];
};
__global__ void k_cvt_all(CvtArgs a, float* __restrict__ dst, const int* __restrict__ dtf) {
    int isf = *dtf;
    int seg = blockIdx.y;
    int i = blockIdx.x * 256 + threadIdx.x;
    if (i < a.n[seg]) dst[a.off[seg] + i] = ldf(a.p[seg], i, isf);
}

// ---------------- embed ----------------
__global__ void k_embed(const void* __restrict__ nf, const void* __restrict__ We,
                        const void* __restrict__ be, float* __restrict__ x, int N,
                        const int* __restrict__ dtf) {
    int isf = *dtf;
    int idx = blockIdx.x * 256 + threadIdx.x;
    if (idx >= N * 32) return;
    int n = idx >> 5, j = idx & 31;
    float v = ldf(nf, n, isf) * ldf(We, j, isf) + ldf(be, j, isf);
    x[idx] = lrelu(v);
}

// ---------------- graph offsets from sorted batch ----------------
__global__ void k_graph_off(const int* __restrict__ batch, int* __restrict__ goff, int N) {
    int n = blockIdx.x * 256 + threadIdx.x;
    if (n >= N) return;
    int bn = batch[n];
    if (n == 0) {
        for (int g = 0; g <= bn; ++g) goff[g] = 0;
    } else {
        int bp = batch[n - 1];
        for (int g = bp + 1; g <= bn; ++g) goff[g] = n;
    }
    if (n == N - 1) {
        for (int g = bn + 1; g <= GG; ++g) goff[g] = N;
    }
}

// ---------------- fallback CSR build (B > 2048 only) ----------------
__global__ void k_hist(const int* __restrict__ dst, unsigned* __restrict__ deg, int E) {
    int e = blockIdx.x * 256 + threadIdx.x;
    if (e >= E) return;
    atomicAdd(&deg[dst[e]], 1u);
}
__global__ void k_scan1(const unsigned* __restrict__ deg, unsigned* __restrict__ excl,
                        unsigned* __restrict__ bsum, int N) {
    __shared__ unsigned s[256];
    int i = blockIdx.x * 256 + threadIdx.x;
    unsigned v = (i < N) ? deg[i] : 0u;
    s[threadIdx.x] = v;
    __syncthreads();
    for (int off = 1; off < 256; off <<= 1) {
        unsigned t = (threadIdx.x >= (unsigned)off) ? s[threadIdx.x - off] : 0u;
        __syncthreads();
        s[threadIdx.x] += t;
        __syncthreads();
    }
    if (i < N) excl[i] = s[threadIdx.x] - v;
    if (threadIdx.x == 255) bsum[blockIdx.x] = s[255];
}
__global__ void k_scan2(const unsigned* __restrict__ bsum, unsigned* __restrict__ boff, int nb) {
    __shared__ unsigned s[256];
    __shared__ unsigned carry;
    if (threadIdx.x == 0) carry = 0u;
    __syncthreads();
    for (int base = 0; base < nb; base += 256) {
        int i = base + threadIdx.x;
        unsigned v = (i < nb) ? bsum[i] : 0u;
        s[threadIdx.x] = v;
        __syncthreads();
        for (int off = 1; off < 256; off <<= 1) {
            unsigned t = (threadIdx.x >= (unsigned)off) ? s[threadIdx.x - off] : 0u;
            __syncthreads();
            s[threadIdx.x] += t;
            __syncthreads();
        }
        if (i < nb) boff[i] = carry + s[threadIdx.x] - v;
        __syncthreads();
        if (threadIdx.x == 0) carry += s[255];
        __syncthreads();
    }
}
__global__ void k_scan3(unsigned* __restrict__ indptr, const unsigned* __restrict__ boff,
                        unsigned* __restrict__ cursor, int N, int E) {
    int i = blockIdx.x * 256 + threadIdx.x;
    if (i >= N) return;
    unsigned v = indptr[i] + boff[i >> 8];
    indptr[i] = v;
    cursor[i] = v;
    if (i == 0) indptr[N] = (unsigned)E;
}
__global__ void k_scatter(const int* __restrict__ src, const int* __restrict__ dst,
                          unsigned* __restrict__ cursor, unsigned* __restrict__ ssrc, int E) {
    int e = blockIdx.x * 256 + threadIdx.x;
    if (e >= E) return;
    unsigned pos = atomicAdd(&cursor[dst[e]], 1u);
    ssrc[pos] = (unsigned)src[e];
}

// ---------------- bucketed CSR build ----------------
__global__ void k_bhist(const int* __restrict__ dst, unsigned* __restrict__ bcnt, int E, int B) {
    __shared__ unsigned h[2048];
    for (int t = threadIdx.x; t < B; t += 256) h[t] = 0;
    __syncthreads();
    int start = blockIdx.x * CHUNK, end = min(E, start + CHUNK);
    for (int e = start + threadIdx.x; e < end; e += 256)
        atomicAdd(&h[dst[e] >> 8], 1u);
    __syncthreads();
    for (int t = threadIdx.x; t < B; t += 256)
        if (h[t]) atomicAdd(&bcnt[t], h[t]);
}

__global__ void k_bscan(const unsigned* __restrict__ bcnt, unsigned* __restrict__ bbase,
                        unsigned* __restrict__ bcur, int B, int E) {
    __shared__ unsigned s[256];
    __shared__ unsigned carry;
    if (threadIdx.x == 0) carry = 0u;
    __syncthreads();
    for (int base = 0; base < B; base += 256) {
        int i = base + threadIdx.x;
        unsigned v = (i < B) ? bcnt[i] : 0u;
        s[threadIdx.x] = v;
        __syncthreads();
        for (int off = 1; off < 256; off <<= 1) {
            unsigned t = (threadIdx.x >= (unsigned)off) ? s[threadIdx.x - off] : 0u;
            __syncthreads();
            s[threadIdx.x] += t;
            __syncthreads();
        }
        if (i < B) {
            unsigned ex = carry + s[threadIdx.x] - v;
            bbase[i] = ex;
            bcur[i] = ex;
        }
        __syncthreads();
        if (threadIdx.x == 0) carry += s[255];
        __syncthreads();
    }
    if (threadIdx.x == 0) bbase[B] = (unsigned)E;
}

__global__ void k_binA(const int* __restrict__ src, const int* __restrict__ dst,
                       unsigned* __restrict__ bcur, unsigned long long* __restrict__ packed,
                       int E, int B) {
    __shared__ unsigned h[2048];
    __shared__ unsigned pos[2048];
    for (int t = threadIdx.x; t < B; t += 256) h[t] = 0;
    __syncthreads();
    int start = blockIdx.x * CHUNK, end = min(E, start + CHUNK);
    for (int e = start + threadIdx.x; e < end; e += 256)
        atomicAdd(&h[dst[e] >> 8], 1u);
    __syncthreads();
    for (int t = threadIdx.x; t < B; t += 256)
        pos[t] = h[t] ? atomicAdd(&bcur[t], h[t]) : 0u;
    __syncthreads();
    for (int e = start + threadIdx.x; e < end; e += 256) {
        int d = dst[e];
        unsigned p = atomicAdd(&pos[d >> 8], 1u);
        packed[p] = ((unsigned long long)(unsigned)d << 32) | (unsigned)src[e];
    }
}

// per-bucket: LDS degree count + scan -> indptr, then bucket-local scatter
__global__ void k_csr(const unsigned long long* __restrict__ packed,
                      const unsigned* __restrict__ bbase,
                      unsigned* __restrict__ indptr,
                      unsigned* __restrict__ ssrc, int N, int E) {
    __shared__ unsigned deg[256];
    __shared__ unsigned scn[256];
    __shared__ unsigned cur[256];
    int g = blockIdx.x, tid = threadIdx.x;
    int n0 = g << 8;
    int cnt = min(256, N - n0);
    deg[tid] = 0;
    __syncthreads();
    unsigned e0 = bbase[g], e1 = bbase[g + 1];
    for (unsigned e = e0 + tid; e < e1; e += 256) {
        int d = (int)(packed[e] >> 32);
        atomicAdd(&deg[d - n0], 1u);
    }
    __syncthreads();
    unsigned v = deg[tid];
    scn[tid] = v;
    __syncthreads();
    for (int off = 1; off < 256; off <<= 1) {
        unsigned t = (tid >= off) ? scn[tid - off] : 0u;
        __syncthreads();
        scn[tid] += t;
        __syncthreads();
    }
    unsigned start = e0 + scn[tid] - v;  // exclusive scan + bucket base
    if (tid < cnt) { indptr[n0 + tid] = start; cur[tid] = start; }
    if (g == (int)gridDim.x - 1 && tid == 0) indptr[N] = (unsigned)E;
    __syncthreads();
    for (unsigned e = e0 + tid; e < e1; e += 256) {
        unsigned long long pk = packed[e];
        int d = (int)(pk >> 32);
        unsigned p = atomicAdd(&cur[d - n0], 1u);
        ssrc[p] = (unsigned)pk;
    }
}

// ---------------- per-node message ----------------
__global__ void k_msg(const float* __restrict__ x, const float* __restrict__ Wm,
                      const float* __restrict__ bm, __hip_bfloat16* __restrict__ m, int N) {
    __shared__ float WL[32 * 32];
    __shared__ float bL[32];
    __shared__ float xs[8][32];
    int tid = threadIdx.x;
    for (int t = tid; t < 1024; t += 256) WL[t] = Wm[t];
    if (tid < 32) bL[tid] = bm[tid];
    int s = tid >> 5, j = tid & 31;
    int n = blockIdx.x * 8 + s;
    if (n < N) xs[s][j] = x[n * 32 + j];
    __syncthreads();
    if (n >= N) return;
    float acc = bL[j];
#pragma unroll
    for (int k = 0; k < 32; ++k) acc += xs[s][k] * WL[k * 32 + j];
    m[n * 32 + j] = __float2bfloat16(lrelu(acc));
}

// ---------------- CSR segment-max ----------------
__global__ void k_aggmax(const unsigned* __restrict__ indptr, const unsigned* __restrict__ ssrc,
                         const __hip_bfloat16* __restrict__ m, float* __restrict__ agg, int N) {
    int tid = threadIdx.x;
    int s = tid >> 5, j = tid & 31;
    int n = blockIdx.x * 8 + s;
    if (n >= N) return;
    unsigned st = indptr[n], en = indptr[n + 1];
    float acc = -INFINITY;
    for (unsigned e = st; e < en; ++e) {
        unsigned sr = ssrc[e];
        acc = fmaxf(acc, b2f(m[sr * 32 + j]));
    }
    agg[n * 32 + j] = (en > st) ? acc : 0.f;
}

// ---------------- f_agg + gate logits + a1 logits ----------------
__global__ void k_fagg(float* __restrict__ x, const float* __restrict__ xg,
                       const float* __restrict__ agg, const int* __restrict__ batch,
                       const float* __restrict__ Wa, const float* __restrict__ ba,
                       const float* __restrict__ Wg, const float* __restrict__ bg,
                       const float* __restrict__ Wa1, const float* __restrict__ ba1,
                       float* __restrict__ logits, float* __restrict__ la1, int N) {
    __shared__ float WL[96 * 32];
    __shared__ float zL[8][96];
    __shared__ float baL[32];
    __shared__ float WgL[32];
    __shared__ float W1L[32];
    __shared__ float bgL, b1L;
    int tid = threadIdx.x;
    for (int t = tid; t < 3072; t += 256) WL[t] = Wa[t];
    if (tid < 32) { baL[tid] = ba[tid]; WgL[tid] = Wg[tid]; W1L[tid] = Wa1[tid]; }
    if (tid == 0) { bgL = bg[0]; b1L = ba1[0]; }
    int s = tid >> 5, j = tid & 31;
    int n = blockIdx.x * 8 + s;
    if (n < N) {
        zL[s][j] = x[n * 32 + j];
        int b = batch[n];
        zL[s][32 + j] = xg[b * 32 + j];
        zL[s][64 + j] = agg[n * 32 + j];
    }
    __syncthreads();
    if (n >= N) return;
    float acc = baL[j];
#pragma unroll
    for (int k = 0; k < 96; ++k) acc += zL[s][k] * WL[k * 32 + j];
    float xn = lrelu(acc) + zL[s][j];
    x[n * 32 + j] = xn;
    float lv = xn * WgL[j];
    float l1 = xn * W1L[j];
#pragma unroll
    for (int off = 16; off; off >>= 1) { lv += __shfl_xor(lv, off); l1 += __shfl_xor(l1, off); }
    if (j == 0) { logits[n] = lv + bgL; la1[n] = l1 + b1L; }
}

// ---------------- per-graph softmax stats (+ zero pooled) ----------------
__global__ void k_gred(const float* __restrict__ logits, const int* __restrict__ goff,
                       float2* __restrict__ garr, float* __restrict__ pooled) {
    __shared__ float red[256];
    int g = blockIdx.x, tid = threadIdx.x;
    int s0 = goff[g], s1 = goff[g + 1];
    float lm = -INFINITY;
    for (int n = s0 + tid; n < s1; n += 256) lm = fmaxf(lm, logits[n]);
    red[tid] = lm;
    __syncthreads();
    for (int off = 128; off; off >>= 1) {
        if (tid < off) red[tid] = fmaxf(red[tid], red[tid + off]);
        __syncthreads();
    }
    float gmax = red[0];
    __syncthreads();
    float ls = 0.f;
    for (int n = s0 + tid; n < s1; n += 256) ls += expf(logits[n] - gmax);
    red[tid] = ls;
    __syncthreads();
    for (int off = 128; off; off >>= 1) {
        if (tid < off) red[tid] += red[tid + off];
        __syncthreads();
    }
    if (tid == 0) {
        float inv = (red[0] > 0.f) ? 1.f / red[0] : 0.f;
        garr[g] = make_float2(gmax, inv);
    }
    if (tid < 32) pooled[g * 32 + tid] = 0.f;
}

// ---------------- gate-weighted feature pooling (wide) ----------------
__global__ void k_pool(const float* __restrict__ x, const float* __restrict__ logits,
                       const int* __restrict__ batch, const float2* __restrict__ garr,
                       const float* __restrict__ Wf, const float* __restrict__ bf,
                       float* __restrict__ pooled, int N) {
    __shared__ float WL[1024];
    __shared__ float bL[32];
    __shared__ float xs[8][32];
    __shared__ float pl[4][32];
    __shared__ int gfirst;
    int tid = threadIdx.x;
    for (int t = tid; t < 1024; t += 256) WL[t] = Wf[t];
    if (tid < 32) bL[tid] = bf[tid];
    for (int t = tid; t < 128; t += 256) pl[t >> 5][t & 31] = 0.f;
    int n0 = blockIdx.x * 256;
    if (tid == 0) gfirst = batch[n0];
    int s = tid >> 5, j = tid & 31;
    __syncthreads();
    int gf = gfirst;
    for (int sub = 0; sub < 32; ++sub) {
        int n = n0 + sub * 8 + s;
        bool valid = n < N;
        __syncthreads();
        if (valid) xs[s][j] = x[n * 32 + j];
        __syncthreads();
        if (valid) {
            float f = bL[j];
#pragma unroll
            for (int k = 0; k < 32; ++k) f += xs[s][k] * WL[k * 32 + j];
            int g = batch[n];
            float2 gm = garr[g];
            float c = expf(logits[n] - gm.x) * gm.y * lrelu(f);
            int gl = g - gf;
            if (gl < 4) atomicAdd(&pl[gl][j], c);
            else atomicAdd(&pooled[g * 32 + j], c);
        }
    }
    __syncthreads();
    for (int t = tid; t < 128; t += 256) {
        float v = pl[t >> 5][t & 31];
        if (v != 0.f) atomicAdd(&pooled[(gf + (t >> 5)) * 32 + (t & 31)], v);
    }
}

// ---------------- xg transform + residual ----------------
__global__ void k_gupd(const float* __restrict__ pooled, const float* __restrict__ xg_in,
                       const float* __restrict__ Wt, const float* __restrict__ bt,
                       float* __restrict__ xg_out) {
    int idx = blockIdx.x * 256 + threadIdx.x;
    if (idx >= GG * 32) return;
    int g = idx >> 5, j = idx & 31;
    float acc = bt[j];
#pragma unroll
    for (int k = 0; k < 32; ++k) acc += pooled[g * 32 + k] * Wt[k * 32 + j];
#pragma unroll
    for (int k = 0; k < 32; ++k) acc += xg_in[g * 32 + k] * Wt[(32 + k) * 32 + j];
    xg_out[idx] = lrelu(acc) + xg_in[idx];
}

// ---------------- final: a1 softmax + value + a0 probs ----------------
__global__ void k_final(const float* __restrict__ logits, const int* __restrict__ goff,
                        const float* __restrict__ xg,
                        const void* __restrict__ Wv, const void* __restrict__ bv,
                        const void* __restrict__ Wa0, const void* __restrict__ ba0,
                        void* __restrict__ out, int N, const int* __restrict__ dtf) {
    __shared__ float red[256];
    int isf = *dtf;
    int g = blockIdx.x, tid = threadIdx.x;
    int s0 = goff[g], s1 = goff[g + 1];
    float lm = -INFINITY;
    for (int n = s0 + tid; n < s1; n += 256) lm = fmaxf(lm, logits[n]);
    red[tid] = lm;
    __syncthreads();
    for (int off = 128; off; off >>= 1) {
        if (tid < off) red[tid] = fmaxf(red[tid], red[tid + off]);
        __syncthreads();
    }
    float gmax = red[0];
    __syncthreads();
    float ls = 0.f;
    for (int n = s0 + tid; n < s1; n += 256) ls += expf(logits[n] - gmax);
    red[tid] = ls;
    __syncthreads();
    for (int off = 128; off; off >>= 1) {
        if (tid < off) red[tid] += red[tid + off];
        __syncthreads();
    }
    float inv = (red[0] > 0.f) ? 1.f / red[0] : 0.f;
    __syncthreads();
    for (int n = s0 + tid; n < s1; n += 256)
        stf(out, 384 + n, expf(logits[n] - gmax) * inv, isf);
    if (tid == 0) {
        float acc = ldf(bv, 0, isf);
        for (int k = 0; k < 32; ++k) acc += xg[g * 32 + k] * ldf(Wv, k, isf);
        stf(out, g, acc, isf);
        float l0 = ldf(ba0, 0, isf), l1 = ldf(ba0, 1, isf);
        for (int k = 0; k < 32; ++k) {
            float xv = xg[g * 32 + k];
            l0 += xv * ldf(Wa0, k * 2, isf);
            l1 += xv * ldf(Wa0, k * 2 + 1, isf);
        }
        float mm = fmaxf(l0, l1);
        float e0 = expf(l0 - mm), e1 = expf(l1 - mm);
        float si = 1.f / (e0 + e1);
        stf(out, 128 + 2 * g, e0 * si, isf);
        stf(out, 128 + 2 * g + 1, e1 * si, isf);
    }
}

extern "C" void kernel_launch(void* const* d_in, const int* in_sizes, int n_in,
                              void* d_out, int out_size, void* d_ws, size_t ws_size,
                              hipStream_t stream) {
    const void* nf      = d_in[0];
    const int*  eidx    = (const int*)d_in[1];
    const int*  batch   = (const int*)d_in[2];
    const void* W_embed = d_in[4];
    const void* b_embed = d_in[5];
    const void* Wm      = d_in[6];
    const void* bm      = d_in[7];
    const void* Wa      = d_in[8];
    const void* ba      = d_in[9];
    const void* Wgate   = d_in[10];
    const void* bgate   = d_in[11];
    const void* Wfeat   = d_in[12];
    const void* bfeat   = d_in[13];
    const void* Wt      = d_in[14];
    const void* bt      = d_in[15];
    const void* W_v     = d_in[16];
    const void* b_v     = d_in[17];
    const void* W_a0    = d_in[18];
    const void* b_a0    = d_in[19];
    const void* W_a1    = d_in[20];
    const void* b_a1    = d_in[21];

    const int N = in_sizes[0];
    const int E = in_sizes[1] / 2;
    const int nWm = in_sizes[6];  // 3*32*32 = 3072
    const int* src = eidx;
    const int* dst = eidx + E;
    const int B = (N + 255) >> 8;

    char* ws = (char*)d_ws;
    size_t off = 0;
    auto alloc = [&](size_t bytes) -> char* {
        char* p = ws + off;
        off = (off + bytes + 255) & ~(size_t)255;
        return p;
    };
    float*          x      = (float*)alloc((size_t)N * 32 * 4);
    // agg aliases packed: packed dead before agg's first write (k_aggmax)
    size_t aggBytes = (size_t)N * 32 * 4;
    size_t pkBytes  = (size_t)E * 8;
    char*  aggRegion = alloc(aggBytes > pkBytes ? aggBytes : pkBytes);
    float*              agg    = (float*)aggRegion;
    unsigned long long* packed = (unsigned long long*)aggRegion;
    __hip_bfloat16* m      = (__hip_bfloat16*)alloc((size_t)N * 32 * 2);
    float*          logits = (float*)alloc((size_t)N * 4);
    float*          la1    = (float*)alloc((size_t)N * 4);
    unsigned*       indptr = (unsigned*)alloc((size_t)(N + 1) * 4);
    unsigned*       cursor = (unsigned*)alloc((size_t)N * 4);
    unsigned*       ssrc   = (unsigned*)alloc((size_t)E * 4);
    const int nb = (N + 255) / 256;
    unsigned*       bsum   = (unsigned*)alloc((size_t)nb * 4);
    unsigned*       boff   = (unsigned*)alloc((size_t)nb * 4);
    unsigned*       bcnt   = (unsigned*)alloc((size_t)(B + 1) * 4);
    unsigned*       bbase  = (unsigned*)alloc((size_t)(B + 1) * 4);
    unsigned*       bcur   = (unsigned*)alloc((size_t)(B + 1) * 4);
    int*            goff   = (int*)alloc((size_t)(GG + 1) * 4);
    float*          xg_a   = (float*)alloc((size_t)GG * 32 * 4);
    float*          xg_b   = (float*)alloc((size_t)GG * 32 * 4);
    float2*         garr   = (float2*)alloc((size_t)GG * 8);
    float*          pooled = (float*)alloc((size_t)GG * 32 * 4);
    int*            dtf    = (int*)alloc(256);
    float*          wcat   = (float*)alloc((size_t)WCAT_N * 4);

    const int nB_n  = (N + 255) / 256;
    const int nB_e  = (E + 255) / 256;
    const int nB_n8 = (N + 7) / 8;
    const int nB_nj = (N * 32 + 255) / 256;
    const int nB_ch = (E + CHUNK - 1) / CHUNK;

    hipMemsetAsync(xg_a, 0, (size_t)GG * 32 * 4, stream);
    hipMemsetAsync(bcnt, 0, (size_t)(B + 1) * 4, stream);

    k_detect<<<1, 256, 0, stream>>>((const unsigned short*)Wm, nWm, dtf);

    CvtArgs ca;
    const void* ps[12] = {Wm, bm, Wa, ba, Wgate, bgate, Wfeat, bfeat, Wt, bt, W_a1, b_a1};
    const int  offs[12] = {OFF_Wm, OFF_bm, OFF_Wa, OFF_ba, OFF_Wg, OFF_bg,
                           OFF_Wf, OFF_bf, OFF_Wt, OFF_bt, OFF_Wa1, OFF_ba1};
    const int  ns[12]  = {3072, 96, 9216, 96, 96, 3, 3072, 96, 6144, 96, 32, 1};
    for (int i = 0; i < 12; ++i) { ca.p[i] = ps[i]; ca.off[i] = offs[i]; ca.n[i] = ns[i]; }
    k_cvt_all<<<dim3(36, 12), 256, 0, stream>>>(ca, wcat, dtf);

    k_embed<<<nB_nj, 256, 0, stream>>>(nf, W_embed, b_embed, x, N, dtf);
    k_graph_off<<<nB_n, 256, 0, stream>>>(batch, goff, N);

    if (B <= 2048) {
        k_bhist<<<nB_ch, 256, 0, stream>>>(dst, bcnt, E, B);
        k_bscan<<<1, 256, 0, stream>>>(bcnt, bbase, bcur, B, E);
        k_binA<<<nB_ch, 256, 0, stream>>>(src, dst, bcur, packed, E, B);
        k_csr<<<B, 256, 0, stream>>>(packed, bbase, indptr, ssrc, N, E);
    } else {
        hipMemsetAsync(cursor, 0, (size_t)N * 4, stream);
        k_hist<<<nB_e, 256, 0, stream>>>(dst, cursor, E);
        k_scan1<<<nb, 256, 0, stream>>>(cursor, indptr, bsum, N);
        k_scan2<<<1, 256, 0, stream>>>(bsum, boff, nb);
        k_scan3<<<nB_n, 256, 0, stream>>>(indptr, boff, cursor, N, E);
        k_scatter<<<nB_e, 256, 0, stream>>>(src, dst, cursor, ssrc, E);
    }

    float* xg_cur = xg_a;
    float* xg_nxt = xg_b;
    for (int i = 0; i < 3; ++i) {
        k_msg<<<nB_n8, 256, 0, stream>>>(x, wcat + OFF_Wm + i * 1024, wcat + OFF_bm + i * 32, m, N);
        k_aggmax<<<nB_n8, 256, 0, stream>>>(indptr, ssrc, m, agg, N);
        k_fagg<<<nB_n8, 256, 0, stream>>>(x, xg_cur, agg, batch,
                                          wcat + OFF_Wa + i * 3072, wcat + OFF_ba + i * 32,
                                          wcat + OFF_Wg + i * 32, wcat + OFF_bg + i,
                                          wcat + OFF_Wa1, wcat + OFF_ba1,
                                          logits, la1, N);
        k_gred<<<GG, 256, 0, stream>>>(logits, goff, garr, pooled);
        k_pool<<<nB_n, 256, 0, stream>>>(x, logits, batch, garr,
                                         wcat + OFF_Wf + i * 1024, wcat + OFF_bf + i * 32,
                                         pooled, N);
        k_gupd<<<(GG * 32 + 255) / 256, 256, 0, stream>>>(pooled, xg_cur,
                                                          wcat + OFF_Wt + i * 2048,
                                                          wcat + OFF_bt + i * 32, xg_nxt);
        float* tmp = xg_cur; xg_cur = xg_nxt; xg_nxt = tmp;
    }

    k_final<<<GG, 256, 0, stream>>>(la1, goff, xg_cur, W_v, b_v, W_a0, b_a0,
                                    d_out, N, dtf);
}

// Round 5
// 1097.373 us; speedup vs baseline: 1.4476x; 1.0352x over previous
//
#include <hip/hip_runtime.h>
#include <hip/hip_bf16.h>

#define GG 128
#define SLOPE 0.01f
#define CHUNK 8192

// wcat element offsets (f32 staged weights)
#define OFF_Wm   0
#define OFF_bm   3072
#define OFF_Wa   3168
#define OFF_ba   12384
#define OFF_Wg   12480
#define OFF_bg   12576
#define OFF_Wf   12592
#define OFF_bf   15664
#define OFF_Wt   15760
#define OFF_bt   21904
#define OFF_Wa1  22000
#define OFF_ba1  22032
#define WCAT_N   22048

__device__ __forceinline__ float lrelu(float v) { return v > 0.f ? v : SLOPE * v; }
__device__ __forceinline__ float b2f(__hip_bfloat16 v) { return __bfloat162float(v); }

__device__ __forceinline__ float ldf(const void* p, int i, int isf) {
    if (isf) return ((const float*)p)[i];
    return __bfloat162float(((const __hip_bfloat16*)p)[i]);
}
__device__ __forceinline__ void stf(void* p, int i, float v, int isf) {
    if (isf) ((float*)p)[i] = v;
    else ((__hip_bfloat16*)p)[i] = __float2bfloat16(v);
}

// ---------------- dtype detection ----------------
__global__ void k_detect(const unsigned short* __restrict__ w, int n, int* __restrict__ flag) {
    __shared__ int bad;
    if (threadIdx.x == 0) bad = 0;
    __syncthreads();
    for (int t = threadIdx.x; t < n; t += 256) {
        unsigned short u = w[t];
        int e = (u >> 7) & 0xFF;
        if (e >= 141) bad = 1;  // benign same-value race
    }
    __syncthreads();
    if (threadIdx.x == 0) { flag[0] = bad; flag[32] = 1; }
}

// ---------------- one-shot weight staging to f32 ----------------
struct CvtArgs {
    const void* p[12];
    int off[12];
    int n[12];
};
__global__ void k_cvt_all(CvtArgs a, float* __restrict__ dst, const int* __restrict__ dtf) {
    int isf = *dtf;
    int seg = blockIdx.y;
    int i = blockIdx.x * 256 + threadIdx.x;
    if (i < a.n[seg]) dst[a.off[seg] + i] = ldf(a.p[seg], i, isf);
}

// ---------------- embed + step-0 message (fused) ----------------
__global__ void k_embed_msg(const void* __restrict__ nf, const void* __restrict__ We,
                            const void* __restrict__ be,
                            const float* __restrict__ Wm0, const float* __restrict__ bm0,
                            float* __restrict__ x, __hip_bfloat16* __restrict__ m, int N,
                            const int* __restrict__ dtf) {
    __shared__ float WL[1024];
    __shared__ float WeL[32], beL[32], bmL[32];
    __shared__ float xs[8][32];
    int isf = *dtf;
    int tid = threadIdx.x;
    for (int t = tid; t < 1024; t += 256) WL[t] = Wm0[t];
    if (tid < 32) { WeL[tid] = ldf(We, tid, isf); beL[tid] = ldf(be, tid, isf); bmL[tid] = bm0[tid]; }
    int s = tid >> 5, j = tid & 31;
    int n = blockIdx.x * 8 + s;
    __syncthreads();
    float xv = 0.f;
    if (n < N) {
        xv = lrelu(ldf(nf, n, isf) * WeL[j] + beL[j]);
        x[n * 32 + j] = xv;
        xs[s][j] = xv;
    }
    __syncthreads();
    if (n >= N) return;
    float acc = bmL[j];
#pragma unroll
    for (int k = 0; k < 32; ++k) acc += xs[s][k] * WL[k * 32 + j];
    m[n * 32 + j] = __float2bfloat16(lrelu(acc));
}

// ---------------- graph offsets from sorted batch ----------------
__global__ void k_graph_off(const int* __restrict__ batch, int* __restrict__ goff, int N) {
    int n = blockIdx.x * 256 + threadIdx.x;
    if (n >= N) return;
    int bn = batch[n];
    if (n == 0) {
        for (int g = 0; g <= bn; ++g) goff[g] = 0;
    } else {
        int bp = batch[n - 1];
        for (int g = bp + 1; g <= bn; ++g) goff[g] = n;
    }
    if (n == N - 1) {
        for (int g = bn + 1; g <= GG; ++g) goff[g] = N;
    }
}

// ---------------- fallback CSR build (B > 2048 only) ----------------
__global__ void k_hist(const int* __restrict__ dst, unsigned* __restrict__ deg, int E) {
    int e = blockIdx.x * 256 + threadIdx.x;
    if (e >= E) return;
    atomicAdd(&deg[dst[e]], 1u);
}
__global__ void k_scan1(const unsigned* __restrict__ deg, unsigned* __restrict__ excl,
                        unsigned* __restrict__ bsum, int N) {
    __shared__ unsigned s[256];
    int i = blockIdx.x * 256 + threadIdx.x;
    unsigned v = (i < N) ? deg[i] : 0u;
    s[threadIdx.x] = v;
    __syncthreads();
    for (int off = 1; off < 256; off <<= 1) {
        unsigned t = (threadIdx.x >= (unsigned)off) ? s[threadIdx.x - off] : 0u;
        __syncthreads();
        s[threadIdx.x] += t;
        __syncthreads();
    }
    if (i < N) excl[i] = s[threadIdx.x] - v;
    if (threadIdx.x == 255) bsum[blockIdx.x] = s[255];
}
__global__ void k_scan2(const unsigned* __restrict__ bsum, unsigned* __restrict__ boff, int nb) {
    __shared__ unsigned s[256];
    __shared__ unsigned carry;
    if (threadIdx.x == 0) carry = 0u;
    __syncthreads();
    for (int base = 0; base < nb; base += 256) {
        int i = base + threadIdx.x;
        unsigned v = (i < nb) ? bsum[i] : 0u;
        s[threadIdx.x] = v;
        __syncthreads();
        for (int off = 1; off < 256; off <<= 1) {
            unsigned t = (threadIdx.x >= (unsigned)off) ? s[threadIdx.x - off] : 0u;
            __syncthreads();
            s[threadIdx.x] += t;
            __syncthreads();
        }
        if (i < nb) boff[i] = carry + s[threadIdx.x] - v;
        __syncthreads();
        if (threadIdx.x == 0) carry += s[255];
        __syncthreads();
    }
}
__global__ void k_scan3(unsigned* __restrict__ indptr, const unsigned* __restrict__ boff,
                        unsigned* __restrict__ cursor, int N, int E) {
    int i = blockIdx.x * 256 + threadIdx.x;
    if (i >= N) return;
    unsigned v = indptr[i] + boff[i >> 8];
    indptr[i] = v;
    cursor[i] = v;
    if (i == 0) indptr[N] = (unsigned)E;
}
__global__ void k_scatter(const int* __restrict__ src, const int* __restrict__ dst,
                          unsigned* __restrict__ cursor, unsigned* __restrict__ ssrc, int E) {
    int e = blockIdx.x * 256 + threadIdx.x;
    if (e >= E) return;
    unsigned pos = atomicAdd(&cursor[dst[e]], 1u);
    ssrc[pos] = (unsigned)src[e];
}

// ---------------- bucketed CSR build ----------------
__global__ void k_bhist(const int* __restrict__ dst, unsigned* __restrict__ bcnt, int E, int B) {
    __shared__ unsigned h[2048];
    for (int t = threadIdx.x; t < B; t += 256) h[t] = 0;
    __syncthreads();
    int start = blockIdx.x * CHUNK, end = min(E, start + CHUNK);
    for (int e = start + threadIdx.x; e < end; e += 256)
        atomicAdd(&h[dst[e] >> 8], 1u);
    __syncthreads();
    for (int t = threadIdx.x; t < B; t += 256)
        if (h[t]) atomicAdd(&bcnt[t], h[t]);
}

__global__ void k_bscan(const unsigned* __restrict__ bcnt, unsigned* __restrict__ bbase,
                        unsigned* __restrict__ bcur, int B, int E) {
    __shared__ unsigned s[256];
    __shared__ unsigned carry;
    if (threadIdx.x == 0) carry = 0u;
    __syncthreads();
    for (int base = 0; base < B; base += 256) {
        int i = base + threadIdx.x;
        unsigned v = (i < B) ? bcnt[i] : 0u;
        s[threadIdx.x] = v;
        __syncthreads();
        for (int off = 1; off < 256; off <<= 1) {
            unsigned t = (threadIdx.x >= (unsigned)off) ? s[threadIdx.x - off] : 0u;
            __syncthreads();
            s[threadIdx.x] += t;
            __syncthreads();
        }
        if (i < B) {
            unsigned ex = carry + s[threadIdx.x] - v;
            bbase[i] = ex;
            bcur[i] = ex;
        }
        __syncthreads();
        if (threadIdx.x == 0) carry += s[255];
        __syncthreads();
    }
    if (threadIdx.x == 0) bbase[B] = (unsigned)E;
}

__global__ void k_binA(const int* __restrict__ src, const int* __restrict__ dst,
                       unsigned* __restrict__ bcur, unsigned long long* __restrict__ packed,
                       int E, int B) {
    __shared__ unsigned h[2048];
    __shared__ unsigned pos[2048];
    for (int t = threadIdx.x; t < B; t += 256) h[t] = 0;
    __syncthreads();
    int start = blockIdx.x * CHUNK, end = min(E, start + CHUNK);
    for (int e = start + threadIdx.x; e < end; e += 256)
        atomicAdd(&h[dst[e] >> 8], 1u);
    __syncthreads();
    for (int t = threadIdx.x; t < B; t += 256)
        pos[t] = h[t] ? atomicAdd(&bcur[t], h[t]) : 0u;
    __syncthreads();
    for (int e = start + threadIdx.x; e < end; e += 256) {
        int d = dst[e];
        unsigned p = atomicAdd(&pos[d >> 8], 1u);
        packed[p] = ((unsigned long long)(unsigned)d << 32) | (unsigned)src[e];
    }
}

// per-bucket: LDS degree count + scan -> indptr, then bucket-local scatter
__global__ void k_csr(const unsigned long long* __restrict__ packed,
                      const unsigned* __restrict__ bbase,
                      unsigned* __restrict__ indptr,
                      unsigned* __restrict__ ssrc, int N, int E) {
    __shared__ unsigned deg[256];
    __shared__ unsigned scn[256];
    __shared__ unsigned cur[256];
    int g = blockIdx.x, tid = threadIdx.x;
    int n0 = g << 8;
    int cnt = min(256, N - n0);
    deg[tid] = 0;
    __syncthreads();
    unsigned e0 = bbase[g], e1 = bbase[g + 1];
    for (unsigned e = e0 + tid; e < e1; e += 256) {
        int d = (int)(packed[e] >> 32);
        atomicAdd(&deg[d - n0], 1u);
    }
    __syncthreads();
    unsigned v = deg[tid];
    scn[tid] = v;
    __syncthreads();
    for (int off = 1; off < 256; off <<= 1) {
        unsigned t = (tid >= off) ? scn[tid - off] : 0u;
        __syncthreads();
        scn[tid] += t;
        __syncthreads();
    }
    unsigned start = e0 + scn[tid] - v;
    if (tid < cnt) { indptr[n0 + tid] = start; cur[tid] = start; }
    if (g == (int)gridDim.x - 1 && tid == 0) indptr[N] = (unsigned)E;
    __syncthreads();
    for (unsigned e = e0 + tid; e < e1; e += 256) {
        unsigned long long pk = packed[e];
        int d = (int)(pk >> 32);
        unsigned p = atomicAdd(&cur[d - n0], 1u);
        ssrc[p] = (unsigned)pk;
    }
}

// ---------------- fused step: gather-max + f_agg + logits + next message ----------------
__global__ void k_step(float* __restrict__ x, const __hip_bfloat16* __restrict__ m_in,
                       __hip_bfloat16* __restrict__ m_out,
                       const float* __restrict__ xg, const int* __restrict__ batch,
                       const unsigned* __restrict__ indptr, const unsigned* __restrict__ ssrc,
                       const float* __restrict__ Wa, const float* __restrict__ ba,
                       const float* __restrict__ Wg, const float* __restrict__ bg,
                       const float* __restrict__ Wa1, const float* __restrict__ ba1,
                       const float* __restrict__ Wm_nx, const float* __restrict__ bm_nx,
                       float* __restrict__ logits, float* __restrict__ la1,
                       int N, int hasNext) {
    __shared__ float WL[3072];
    __shared__ float WmL[1024];
    __shared__ float zL[8][96];
    __shared__ float xnL[8][32];
    __shared__ float baL[32], WgL[32], W1L[32], bmL[32];
    __shared__ float bgL, b1L;
    int tid = threadIdx.x;
    for (int t = tid; t < 3072; t += 256) WL[t] = Wa[t];
    if (hasNext) {
        for (int t = tid; t < 1024; t += 256) WmL[t] = Wm_nx[t];
        if (tid < 32) bmL[tid] = bm_nx[tid];
    }
    if (tid < 32) { baL[tid] = ba[tid]; WgL[tid] = Wg[tid]; W1L[tid] = Wa1[tid]; }
    if (tid == 0) { bgL = bg[0]; b1L = ba1[0]; }
    int s = tid >> 5, j = tid & 31;
    int n = blockIdx.x * 8 + s;
    bool valid = n < N;
    if (valid) {
        zL[s][j] = x[n * 32 + j];
        zL[s][32 + j] = xg[batch[n] * 32 + j];
    }
    // gather-max: 16 lanes per edge row, 2 edges in flight (bfloat162 loads)
    unsigned st = 0, en = 0;
    if (valid) { st = indptr[n]; en = indptr[n + 1]; }
    int c = j & 15, half = (j >> 4) & 1;
    const __hip_bfloat162* m2 = (const __hip_bfloat162*)m_in;
    float ax = -INFINITY, ay = -INFINITY;
    for (unsigned e = st + half; e < en; e += 2) {
        unsigned sr = ssrc[e];
        __hip_bfloat162 v = m2[sr * 16 + c];
        ax = fmaxf(ax, b2f(v.x));
        ay = fmaxf(ay, b2f(v.y));
    }
    ax = fmaxf(ax, __shfl_xor(ax, 16));
    ay = fmaxf(ay, __shfl_xor(ay, 16));
    if (valid && half == 0) {
        bool empty = (st == en);
        zL[s][64 + 2 * c]     = empty ? 0.f : ax;
        zL[s][64 + 2 * c + 1] = empty ? 0.f : ay;
    }
    __syncthreads();
    if (valid) {
        float acc = baL[j];
#pragma unroll
        for (int k = 0; k < 96; ++k) acc += zL[s][k] * WL[k * 32 + j];
        float xn = lrelu(acc) + zL[s][j];
        x[n * 32 + j] = xn;
        xnL[s][j] = xn;
        float lv = xn * WgL[j];
        float l1 = xn * W1L[j];
#pragma unroll
        for (int off = 16; off; off >>= 1) { lv += __shfl_xor(lv, off); l1 += __shfl_xor(l1, off); }
        if (j == 0) { logits[n] = lv + bgL; la1[n] = l1 + b1L; }
    }
    __syncthreads();
    if (valid && hasNext) {
        float a2 = bmL[j];
#pragma unroll
        for (int k = 0; k < 32; ++k) a2 += xnL[s][k] * WmL[k * 32 + j];
        m_out[n * 32 + j] = __float2bfloat16(lrelu(a2));
    }
}

// ---------------- per-graph softmax stats (+ zero pooled) ----------------
__global__ void k_gred(const float* __restrict__ logits, const int* __restrict__ goff,
                       float2* __restrict__ garr, float* __restrict__ pooled) {
    __shared__ float red[256];
    int g = blockIdx.x, tid = threadIdx.x;
    int s0 = goff[g], s1 = goff[g + 1];
    float lm = -INFINITY;
    for (int n = s0 + tid; n < s1; n += 256) lm = fmaxf(lm, logits[n]);
    red[tid] = lm;
    __syncthreads();
    for (int off = 128; off; off >>= 1) {
        if (tid < off) red[tid] = fmaxf(red[tid], red[tid + off]);
        __syncthreads();
    }
    float gmax = red[0];
    __syncthreads();
    float ls = 0.f;
    for (int n = s0 + tid; n < s1; n += 256) ls += expf(logits[n] - gmax);
    red[tid] = ls;
    __syncthreads();
    for (int off = 128; off; off >>= 1) {
        if (tid < off) red[tid] += red[tid + off];
        __syncthreads();
    }
    if (tid == 0) {
        float inv = (red[0] > 0.f) ? 1.f / red[0] : 0.f;
        garr[g] = make_float2(gmax, inv);
    }
    if (tid < 32) pooled[g * 32 + tid] = 0.f;
}

// ---------------- gate-weighted feature pooling (wide) ----------------
__global__ void k_pool(const float* __restrict__ x, const float* __restrict__ logits,
                       const int* __restrict__ batch, const float2* __restrict__ garr,
                       const float* __restrict__ Wf, const float* __restrict__ bf,
                       float* __restrict__ pooled, int N) {
    __shared__ float WL[1024];
    __shared__ float bL[32];
    __shared__ float xs[8][32];
    __shared__ float pl[4][32];
    __shared__ int gfirst;
    int tid = threadIdx.x;
    for (int t = tid; t < 1024; t += 256) WL[t] = Wf[t];
    if (tid < 32) bL[tid] = bf[tid];
    for (int t = tid; t < 128; t += 256) pl[t >> 5][t & 31] = 0.f;
    int n0 = blockIdx.x * 256;
    if (tid == 0) gfirst = batch[n0];
    int s = tid >> 5, j = tid & 31;
    __syncthreads();
    int gf = gfirst;
    for (int sub = 0; sub < 32; ++sub) {
        int n = n0 + sub * 8 + s;
        bool valid = n < N;
        __syncthreads();
        if (valid) xs[s][j] = x[n * 32 + j];
        __syncthreads();
        if (valid) {
            float f = bL[j];
#pragma unroll
            for (int k = 0; k < 32; ++k) f += xs[s][k] * WL[k * 32 + j];
            int g = batch[n];
            float2 gm = garr[g];
            float c = expf(logits[n] - gm.x) * gm.y * lrelu(f);
            int gl = g - gf;
            if (gl < 4) atomicAdd(&pl[gl][j], c);
            else atomicAdd(&pooled[g * 32 + j], c);
        }
    }
    __syncthreads();
    for (int t = tid; t < 128; t += 256) {
        float v = pl[t >> 5][t & 31];
        if (v != 0.f) atomicAdd(&pooled[(gf + (t >> 5)) * 32 + (t & 31)], v);
    }
}

// ---------------- xg transform + residual ----------------
__global__ void k_gupd(const float* __restrict__ pooled, const float* __restrict__ xg_in,
                       const float* __restrict__ Wt, const float* __restrict__ bt,
                       float* __restrict__ xg_out) {
    int idx = blockIdx.x * 256 + threadIdx.x;
    if (idx >= GG * 32) return;
    int g = idx >> 5, j = idx & 31;
    float acc = bt[j];
#pragma unroll
    for (int k = 0; k < 32; ++k) acc += pooled[g * 32 + k] * Wt[k * 32 + j];
#pragma unroll
    for (int k = 0; k < 32; ++k) acc += xg_in[g * 32 + k] * Wt[(32 + k) * 32 + j];
    xg_out[idx] = lrelu(acc) + xg_in[idx];
}

// ---------------- final: a1 softmax + value + a0 probs ----------------
__global__ void k_final(const float* __restrict__ logits, const int* __restrict__ goff,
                        const float* __restrict__ xg,
                        const void* __restrict__ Wv, const void* __restrict__ bv,
                        const void* __restrict__ Wa0, const void* __restrict__ ba0,
                        void* __restrict__ out, int N, const int* __restrict__ dtf) {
    __shared__ float red[256];
    int isf = *dtf;
    int g = blockIdx.x, tid = threadIdx.x;
    int s0 = goff[g], s1 = goff[g + 1];
    float lm = -INFINITY;
    for (int n = s0 + tid; n < s1; n += 256) lm = fmaxf(lm, logits[n]);
    red[tid] = lm;
    __syncthreads();
    for (int off = 128; off; off >>= 1) {
        if (tid < off) red[tid] = fmaxf(red[tid], red[tid + off]);
        __syncthreads();
    }
    float gmax = red[0];
    __syncthreads();
    float ls = 0.f;
    for (int n = s0 + tid; n < s1; n += 256) ls += expf(logits[n] - gmax);
    red[tid] = ls;
    __syncthreads();
    for (int off = 128; off; off >>= 1) {
        if (tid < off) red[tid] += red[tid + off];
        __syncthreads();
    }
    float inv = (red[0] > 0.f) ? 1.f / red[0] : 0.f;
    __syncthreads();
    for (int n = s0 + tid; n < s1; n += 256)
        stf(out, 384 + n, expf(logits[n] - gmax) * inv, isf);
    if (tid == 0) {
        float acc = ldf(bv, 0, isf);
        for (int k = 0; k < 32; ++k) acc += xg[g * 32 + k] * ldf(Wv, k, isf);
        stf(out, g, acc, isf);
        float l0 = ldf(ba0, 0, isf), l1 = ldf(ba0, 1, isf);
        for (int k = 0; k < 32; ++k) {
            float xv = xg[g * 32 + k];
            l0 += xv * ldf(Wa0, k * 2, isf);
            l1 += xv * ldf(Wa0, k * 2 + 1, isf);
        }
        float mm = fmaxf(l0, l1);
        float e0 = expf(l0 - mm), e1 = expf(l1 - mm);
        float si = 1.f / (e0 + e1);
        stf(out, 128 + 2 * g, e0 * si, isf);
        stf(out, 128 + 2 * g + 1, e1 * si, isf);
    }
}

extern "C" void kernel_launch(void* const* d_in, const int* in_sizes, int n_in,
                              void* d_out, int out_size, void* d_ws, size_t ws_size,
                              hipStream_t stream) {
    const void* nf      = d_in[0];
    const int*  eidx    = (const int*)d_in[1];
    const int*  batch   = (const int*)d_in[2];
    const void* W_embed = d_in[4];
    const void* b_embed = d_in[5];
    const void* Wm      = d_in[6];
    const void* bm      = d_in[7];
    const void* Wa      = d_in[8];
    const void* ba      = d_in[9];
    const void* Wgate   = d_in[10];
    const void* bgate   = d_in[11];
    const void* Wfeat   = d_in[12];
    const void* bfeat   = d_in[13];
    const void* Wt      = d_in[14];
    const void* bt      = d_in[15];
    const void* W_v     = d_in[16];
    const void* b_v     = d_in[17];
    const void* W_a0    = d_in[18];
    const void* b_a0    = d_in[19];
    const void* W_a1    = d_in[20];
    const void* b_a1    = d_in[21];

    const int N = in_sizes[0];
    const int E = in_sizes[1] / 2;
    const int nWm = in_sizes[6];  // 3*32*32 = 3072
    const int* src = eidx;
    const int* dst = eidx + E;
    const int B = (N + 255) >> 8;

    char* ws = (char*)d_ws;
    size_t off = 0;
    auto alloc = [&](size_t bytes) -> char* {
        char* p = ws + off;
        off = (off + bytes + 255) & ~(size_t)255;
        return p;
    };
    float*          x      = (float*)alloc((size_t)N * 32 * 4);
    // packed (E*8 B) aliases m_a+m_b (2 * N*32*2 B): packed dead after k_csr,
    // m first written by k_embed_msg which launches after k_csr.
    size_t mBytes  = (size_t)N * 32 * 2;
    size_t pkBytes = (size_t)E * 8;
    size_t rBytes  = (2 * mBytes > pkBytes) ? 2 * mBytes : pkBytes;
    char*  mRegion = alloc(rBytes);
    unsigned long long* packed = (unsigned long long*)mRegion;
    __hip_bfloat16*     m_a    = (__hip_bfloat16*)mRegion;
    __hip_bfloat16*     m_b    = (__hip_bfloat16*)(mRegion + mBytes);
    float*          logits = (float*)alloc((size_t)N * 4);
    float*          la1    = (float*)alloc((size_t)N * 4);
    unsigned*       indptr = (unsigned*)alloc((size_t)(N + 1) * 4);
    unsigned*       cursor = (unsigned*)alloc((size_t)N * 4);
    unsigned*       ssrc   = (unsigned*)alloc((size_t)E * 4);
    const int nb = (N + 255) / 256;
    unsigned*       bsum   = (unsigned*)alloc((size_t)nb * 4);
    unsigned*       boff   = (unsigned*)alloc((size_t)nb * 4);
    unsigned*       bcnt   = (unsigned*)alloc((size_t)(B + 1) * 4);
    unsigned*       bbase  = (unsigned*)alloc((size_t)(B + 1) * 4);
    unsigned*       bcur   = (unsigned*)alloc((size_t)(B + 1) * 4);
    int*            goff   = (int*)alloc((size_t)(GG + 1) * 4);
    float*          xg_a   = (float*)alloc((size_t)GG * 32 * 4);
    float*          xg_b   = (float*)alloc((size_t)GG * 32 * 4);
    float2*         garr   = (float2*)alloc((size_t)GG * 8);
    float*          pooled = (float*)alloc((size_t)GG * 32 * 4);
    int*            dtf    = (int*)alloc(256);
    float*          wcat   = (float*)alloc((size_t)WCAT_N * 4);

    const int nB_n  = (N + 255) / 256;
    const int nB_e  = (E + 255) / 256;
    const int nB_n8 = (N + 7) / 8;
    const int nB_ch = (E + CHUNK - 1) / CHUNK;

    hipMemsetAsync(xg_a, 0, (size_t)GG * 32 * 4, stream);
    hipMemsetAsync(bcnt, 0, (size_t)(B + 1) * 4, stream);

    k_detect<<<1, 256, 0, stream>>>((const unsigned short*)Wm, nWm, dtf);

    CvtArgs ca;
    const void* ps[12] = {Wm, bm, Wa, ba, Wgate, bgate, Wfeat, bfeat, Wt, bt, W_a1, b_a1};
    const int  offs[12] = {OFF_Wm, OFF_bm, OFF_Wa, OFF_ba, OFF_Wg, OFF_bg,
                           OFF_Wf, OFF_bf, OFF_Wt, OFF_bt, OFF_Wa1, OFF_ba1};
    const int  ns[12]  = {3072, 96, 9216, 96, 96, 3, 3072, 96, 6144, 96, 32, 1};
    for (int i = 0; i < 12; ++i) { ca.p[i] = ps[i]; ca.off[i] = offs[i]; ca.n[i] = ns[i]; }
    k_cvt_all<<<dim3(36, 12), 256, 0, stream>>>(ca, wcat, dtf);

    k_graph_off<<<nB_n, 256, 0, stream>>>(batch, goff, N);

    // CSR build first (packed aliases m buffers; m written after)
    if (B <= 2048) {
        k_bhist<<<nB_ch, 256, 0, stream>>>(dst, bcnt, E, B);
        k_bscan<<<1, 256, 0, stream>>>(bcnt, bbase, bcur, B, E);
        k_binA<<<nB_ch, 256, 0, stream>>>(src, dst, bcur, packed, E, B);
        k_csr<<<B, 256, 0, stream>>>(packed, bbase, indptr, ssrc, N, E);
    } else {
        hipMemsetAsync(cursor, 0, (size_t)N * 4, stream);
        k_hist<<<nB_e, 256, 0, stream>>>(dst, cursor, E);
        k_scan1<<<nb, 256, 0, stream>>>(cursor, indptr, bsum, N);
        k_scan2<<<1, 256, 0, stream>>>(bsum, boff, nb);
        k_scan3<<<nB_n, 256, 0, stream>>>(indptr, boff, cursor, N, E);
        k_scatter<<<nB_e, 256, 0, stream>>>(src, dst, cursor, ssrc, E);
    }

    // embed + step-0 message
    k_embed_msg<<<nB_n8, 256, 0, stream>>>(nf, W_embed, b_embed,
                                           wcat + OFF_Wm, wcat + OFF_bm, x, m_a, N, dtf);

    float* xg_cur = xg_a;
    float* xg_nxt = xg_b;
    __hip_bfloat16* m_cur = m_a;
    __hip_bfloat16* m_nxt = m_b;
    for (int i = 0; i < 3; ++i) {
        int hasNext = (i < 2) ? 1 : 0;
        k_step<<<nB_n8, 256, 0, stream>>>(x, m_cur, m_nxt, xg_cur, batch, indptr, ssrc,
                                          wcat + OFF_Wa + i * 3072, wcat + OFF_ba + i * 32,
                                          wcat + OFF_Wg + i * 32, wcat + OFF_bg + i,
                                          wcat + OFF_Wa1, wcat + OFF_ba1,
                                          wcat + OFF_Wm + (i + 1) * 1024,
                                          wcat + OFF_bm + (i + 1) * 32,
                                          logits, la1, N, hasNext);
        k_gred<<<GG, 256, 0, stream>>>(logits, goff, garr, pooled);
        k_pool<<<nB_n, 256, 0, stream>>>(x, logits, batch, garr,
                                         wcat + OFF_Wf + i * 1024, wcat + OFF_bf + i * 32,
                                         pooled, N);
        k_gupd<<<(GG * 32 + 255) / 256, 256, 0, stream>>>(pooled, xg_cur,
                                                          wcat + OFF_Wt + i * 2048,
                                                          wcat + OFF_bt + i * 32, xg_nxt);
        float* tmp = xg_cur; xg_cur = xg_nxt; xg_nxt = tmp;
        __hip_bfloat16* tm = m_cur; m_cur = m_nxt; m_nxt = tm;
    }

    k_final<<<GG, 256, 0, stream>>>(la1, goff, xg_cur, W_v, b_v, W_a0, b_a0,
                                    d_out, N, dtf);
}

// Round 6
// 919.374 us; speedup vs baseline: 1.7279x; 1.1936x over previous
//
#include <hip/hip_runtime.h>
#include <hip/hip_bf16.h>

#define GG 128
#define SLOPE 0.01f
#define CHUNK 8192

// wcat element offsets (f32 staged weights)
#define OFF_Wm   0
#define OFF_bm   3072
#define OFF_Wa   3168
#define OFF_ba   12384
#define OFF_Wg   12480
#define OFF_bg   12576
#define OFF_Wf   12592
#define OFF_bf   15664
#define OFF_Wt   15760
#define OFF_bt   21904
#define OFF_Wa1  22000
#define OFF_ba1  22032
#define WCAT_N   22048

__device__ __forceinline__ float lrelu(float v) { return v > 0.f ? v : SLOPE * v; }
__device__ __forceinline__ float b2f(__hip_bfloat16 v) { return __bfloat162float(v); }

__device__ __forceinline__ float ldf(const void* p, int i, int isf) {
    if (isf) return ((const float*)p)[i];
    return __bfloat162float(((const __hip_bfloat16*)p)[i]);
}
__device__ __forceinline__ void stf(void* p, int i, float v, int isf) {
    if (isf) ((float*)p)[i] = v;
    else ((__hip_bfloat16*)p)[i] = __float2bfloat16(v);
}

// ---------------- dtype detection ----------------
__global__ void k_detect(const unsigned short* __restrict__ w, int n, int* __restrict__ flag) {
    __shared__ int bad;
    if (threadIdx.x == 0) bad = 0;
    __syncthreads();
    for (int t = threadIdx.x; t < n; t += 256) {
        unsigned short u = w[t];
        int e = (u >> 7) & 0xFF;
        if (e >= 141) bad = 1;  // benign same-value race
    }
    __syncthreads();
    if (threadIdx.x == 0) { flag[0] = bad; flag[32] = 1; }
}

// ---------------- one-shot weight staging to f32 ----------------
struct CvtArgs {
    const void* p[12];
    int off[12];
    int n[12];
};
__global__ void k_cvt_all(CvtArgs a, float* __restrict__ dst, const int* __restrict__ dtf) {
    int isf = *dtf;
    int seg = blockIdx.y;
    int i = blockIdx.x * 256 + threadIdx.x;
    if (i < a.n[seg]) dst[a.off[seg] + i] = ldf(a.p[seg], i, isf);
}

// ---------------- embed + step-0 message (fused) ----------------
__global__ void k_embed_msg(const void* __restrict__ nf, const void* __restrict__ We,
                            const void* __restrict__ be,
                            const float* __restrict__ Wm0, const float* __restrict__ bm0,
                            float* __restrict__ x, __hip_bfloat16* __restrict__ m, int N,
                            const int* __restrict__ dtf) {
    __shared__ float WL[1024];
    __shared__ float WeL[32], beL[32], bmL[32];
    __shared__ float xs[8][32];
    int isf = *dtf;
    int tid = threadIdx.x;
    for (int t = tid; t < 1024; t += 256) WL[t] = Wm0[t];
    if (tid < 32) { WeL[tid] = ldf(We, tid, isf); beL[tid] = ldf(be, tid, isf); bmL[tid] = bm0[tid]; }
    int s = tid >> 5, j = tid & 31;
    int n = blockIdx.x * 8 + s;
    __syncthreads();
    float xv = 0.f;
    if (n < N) {
        xv = lrelu(ldf(nf, n, isf) * WeL[j] + beL[j]);
        x[n * 32 + j] = xv;
        xs[s][j] = xv;
    }
    __syncthreads();
    if (n >= N) return;
    float acc = bmL[j];
#pragma unroll
    for (int k = 0; k < 32; ++k) acc += xs[s][k] * WL[k * 32 + j];
    m[n * 32 + j] = __float2bfloat16(lrelu(acc));
}

// ---------------- graph offsets from sorted batch ----------------
__global__ void k_graph_off(const int* __restrict__ batch, int* __restrict__ goff, int N) {
    int n = blockIdx.x * 256 + threadIdx.x;
    if (n >= N) return;
    int bn = batch[n];
    if (n == 0) {
        for (int g = 0; g <= bn; ++g) goff[g] = 0;
    } else {
        int bp = batch[n - 1];
        for (int g = bp + 1; g <= bn; ++g) goff[g] = n;
    }
    if (n == N - 1) {
        for (int g = bn + 1; g <= GG; ++g) goff[g] = N;
    }
}

// ---------------- fallback CSR build (B > 2048 only) ----------------
__global__ void k_hist(const int* __restrict__ dst, unsigned* __restrict__ deg, int E) {
    int e = blockIdx.x * 256 + threadIdx.x;
    if (e >= E) return;
    atomicAdd(&deg[dst[e]], 1u);
}
__global__ void k_scan1(const unsigned* __restrict__ deg, unsigned* __restrict__ excl,
                        unsigned* __restrict__ bsum, int N) {
    __shared__ unsigned s[256];
    int i = blockIdx.x * 256 + threadIdx.x;
    unsigned v = (i < N) ? deg[i] : 0u;
    s[threadIdx.x] = v;
    __syncthreads();
    for (int off = 1; off < 256; off <<= 1) {
        unsigned t = (threadIdx.x >= (unsigned)off) ? s[threadIdx.x - off] : 0u;
        __syncthreads();
        s[threadIdx.x] += t;
        __syncthreads();
    }
    if (i < N) excl[i] = s[threadIdx.x] - v;
    if (threadIdx.x == 255) bsum[blockIdx.x] = s[255];
}
__global__ void k_scan2(const unsigned* __restrict__ bsum, unsigned* __restrict__ boff, int nb) {
    __shared__ unsigned s[256];
    __shared__ unsigned carry;
    if (threadIdx.x == 0) carry = 0u;
    __syncthreads();
    for (int base = 0; base < nb; base += 256) {
        int i = base + threadIdx.x;
        unsigned v = (i < nb) ? bsum[i] : 0u;
        s[threadIdx.x] = v;
        __syncthreads();
        for (int off = 1; off < 256; off <<= 1) {
            unsigned t = (threadIdx.x >= (unsigned)off) ? s[threadIdx.x - off] : 0u;
            __syncthreads();
            s[threadIdx.x] += t;
            __syncthreads();
        }
        if (i < nb) boff[i] = carry + s[threadIdx.x] - v;
        __syncthreads();
        if (threadIdx.x == 0) carry += s[255];
        __syncthreads();
    }
}
__global__ void k_scan3(unsigned* __restrict__ indptr, const unsigned* __restrict__ boff,
                        unsigned* __restrict__ cursor, int N, int E) {
    int i = blockIdx.x * 256 + threadIdx.x;
    if (i >= N) return;
    unsigned v = indptr[i] + boff[i >> 8];
    indptr[i] = v;
    cursor[i] = v;
    if (i == 0) indptr[N] = (unsigned)E;
}
__global__ void k_scatter(const int* __restrict__ src, const int* __restrict__ dst,
                          unsigned* __restrict__ cursor, unsigned* __restrict__ ssrc, int E) {
    int e = blockIdx.x * 256 + threadIdx.x;
    if (e >= E) return;
    unsigned pos = atomicAdd(&cursor[dst[e]], 1u);
    ssrc[pos] = (unsigned)src[e];
}

// ---------------- bucketed CSR build ----------------
__global__ void k_bhist(const int* __restrict__ dst, unsigned* __restrict__ bcnt, int E, int B) {
    __shared__ unsigned h[2048];
    for (int t = threadIdx.x; t < B; t += 256) h[t] = 0;
    __syncthreads();
    int start = blockIdx.x * CHUNK, end = min(E, start + CHUNK);
    for (int e = start + threadIdx.x; e < end; e += 256)
        atomicAdd(&h[dst[e] >> 8], 1u);
    __syncthreads();
    for (int t = threadIdx.x; t < B; t += 256)
        if (h[t]) atomicAdd(&bcnt[t], h[t]);
}

__global__ void k_bscan(const unsigned* __restrict__ bcnt, unsigned* __restrict__ bbase,
                        unsigned* __restrict__ bcur, int B, int E) {
    __shared__ unsigned s[256];
    __shared__ unsigned carry;
    if (threadIdx.x == 0) carry = 0u;
    __syncthreads();
    for (int base = 0; base < B; base += 256) {
        int i = base + threadIdx.x;
        unsigned v = (i < B) ? bcnt[i] : 0u;
        s[threadIdx.x] = v;
        __syncthreads();
        for (int off = 1; off < 256; off <<= 1) {
            unsigned t = (threadIdx.x >= (unsigned)off) ? s[threadIdx.x - off] : 0u;
            __syncthreads();
            s[threadIdx.x] += t;
            __syncthreads();
        }
        if (i < B) {
            unsigned ex = carry + s[threadIdx.x] - v;
            bbase[i] = ex;
            bcur[i] = ex;
        }
        __syncthreads();
        if (threadIdx.x == 0) carry += s[255];
        __syncthreads();
    }
    if (threadIdx.x == 0) bbase[B] = (unsigned)E;
}

__global__ void k_binA(const int* __restrict__ src, const int* __restrict__ dst,
                       unsigned* __restrict__ bcur, unsigned long long* __restrict__ packed,
                       int E, int B) {
    __shared__ unsigned h[2048];
    __shared__ unsigned pos[2048];
    for (int t = threadIdx.x; t < B; t += 256) h[t] = 0;
    __syncthreads();
    int start = blockIdx.x * CHUNK, end = min(E, start + CHUNK);
    for (int e = start + threadIdx.x; e < end; e += 256)
        atomicAdd(&h[dst[e] >> 8], 1u);
    __syncthreads();
    for (int t = threadIdx.x; t < B; t += 256)
        pos[t] = h[t] ? atomicAdd(&bcur[t], h[t]) : 0u;
    __syncthreads();
    for (int e = start + threadIdx.x; e < end; e += 256) {
        int d = dst[e];
        unsigned p = atomicAdd(&pos[d >> 8], 1u);
        packed[p] = ((unsigned long long)(unsigned)d << 32) | (unsigned)src[e];
    }
}

// per-bucket: LDS degree count + scan -> indptr, then bucket-local scatter
__global__ void k_csr(const unsigned long long* __restrict__ packed,
                      const unsigned* __restrict__ bbase,
                      unsigned* __restrict__ indptr,
                      unsigned* __restrict__ ssrc, int N, int E) {
    __shared__ unsigned deg[256];
    __shared__ unsigned scn[256];
    __shared__ unsigned cur[256];
    int g = blockIdx.x, tid = threadIdx.x;
    int n0 = g << 8;
    int cnt = min(256, N - n0);
    deg[tid] = 0;
    __syncthreads();
    unsigned e0 = bbase[g], e1 = bbase[g + 1];
    for (unsigned e = e0 + tid; e < e1; e += 256) {
        int d = (int)(packed[e] >> 32);
        atomicAdd(&deg[d - n0], 1u);
    }
    __syncthreads();
    unsigned v = deg[tid];
    scn[tid] = v;
    __syncthreads();
    for (int off = 1; off < 256; off <<= 1) {
        unsigned t = (tid >= off) ? scn[tid - off] : 0u;
        __syncthreads();
        scn[tid] += t;
        __syncthreads();
    }
    unsigned start = e0 + scn[tid] - v;
    if (tid < cnt) { indptr[n0 + tid] = start; cur[tid] = start; }
    if (g == (int)gridDim.x - 1 && tid == 0) indptr[N] = (unsigned)E;
    __syncthreads();
    for (unsigned e = e0 + tid; e < e1; e += 256) {
        unsigned long long pk = packed[e];
        int d = (int)(pk >> 32);
        unsigned p = atomicAdd(&cur[d - n0], 1u);
        ssrc[p] = (unsigned)pk;
    }
}

// ---------------- fused step: gather-max + f_agg + logits + next message ----------------
// Gather restructured for MLP: 4 independent edge loads in flight per 16-lane half
// (clamped-duplicate tail — duplicates are idempotent under max).
__global__ void k_step(float* __restrict__ x, const __hip_bfloat16* __restrict__ m_in,
                       __hip_bfloat16* __restrict__ m_out,
                       const float* __restrict__ xg, const int* __restrict__ batch,
                       const unsigned* __restrict__ indptr, const unsigned* __restrict__ ssrc,
                       const float* __restrict__ Wa, const float* __restrict__ ba,
                       const float* __restrict__ Wg, const float* __restrict__ bg,
                       const float* __restrict__ Wa1, const float* __restrict__ ba1,
                       const float* __restrict__ Wm_nx, const float* __restrict__ bm_nx,
                       float* __restrict__ logits, float* __restrict__ la1,
                       int N, int hasNext) {
    __shared__ float WL[3072];
    __shared__ float WmL[1024];
    __shared__ float zL[8][96];
    __shared__ float xnL[8][32];
    __shared__ float baL[32], WgL[32], W1L[32], bmL[32];
    __shared__ float bgL, b1L;
    int tid = threadIdx.x;
    for (int t = tid; t < 3072; t += 256) WL[t] = Wa[t];
    if (hasNext) {
        for (int t = tid; t < 1024; t += 256) WmL[t] = Wm_nx[t];
        if (tid < 32) bmL[tid] = bm_nx[tid];
    }
    if (tid < 32) { baL[tid] = ba[tid]; WgL[tid] = Wg[tid]; W1L[tid] = Wa1[tid]; }
    if (tid == 0) { bgL = bg[0]; b1L = ba1[0]; }
    int s = tid >> 5, j = tid & 31;
    int n = blockIdx.x * 8 + s;
    bool valid = n < N;
    if (valid) {
        zL[s][j] = x[n * 32 + j];
        zL[s][32 + j] = xg[batch[n] * 32 + j];
    }
    unsigned st = 0, en = 0;
    if (valid) { st = indptr[n]; en = indptr[n + 1]; }
    int c = j & 15, half = (j >> 4) & 1;
    const __hip_bfloat162* m2 = (const __hip_bfloat162*)m_in;
    float ax = -INFINITY, ay = -INFINITY;
    // halves interleave quads: half0 -> [st..st+3],[st+8..], half1 -> [st+4..st+7],...
    for (unsigned eb = st + half * 4; eb < en; eb += 8) {
        unsigned last = en - 1;
        unsigned e1i = min(eb + 1, last);
        unsigned e2i = min(eb + 2, last);
        unsigned e3i = min(eb + 3, last);
        unsigned s0 = ssrc[eb];
        unsigned s1 = ssrc[e1i];
        unsigned s2 = ssrc[e2i];
        unsigned s3 = ssrc[e3i];
        __hip_bfloat162 v0 = m2[s0 * 16 + c];
        __hip_bfloat162 v1 = m2[s1 * 16 + c];
        __hip_bfloat162 v2 = m2[s2 * 16 + c];
        __hip_bfloat162 v3 = m2[s3 * 16 + c];
        ax = fmaxf(fmaxf(fmaxf(b2f(v0.x), b2f(v1.x)), fmaxf(b2f(v2.x), b2f(v3.x))), ax);
        ay = fmaxf(fmaxf(fmaxf(b2f(v0.y), b2f(v1.y)), fmaxf(b2f(v2.y), b2f(v3.y))), ay);
    }
    ax = fmaxf(ax, __shfl_xor(ax, 16));
    ay = fmaxf(ay, __shfl_xor(ay, 16));
    if (valid && half == 0) {
        bool empty = (st == en);
        zL[s][64 + 2 * c]     = empty ? 0.f : ax;
        zL[s][64 + 2 * c + 1] = empty ? 0.f : ay;
    }
    __syncthreads();
    if (valid) {
        float acc = baL[j];
#pragma unroll
        for (int k = 0; k < 96; ++k) acc += zL[s][k] * WL[k * 32 + j];
        float xn = lrelu(acc) + zL[s][j];
        x[n * 32 + j] = xn;
        xnL[s][j] = xn;
        float lv = xn * WgL[j];
        float l1 = xn * W1L[j];
#pragma unroll
        for (int off = 16; off; off >>= 1) { lv += __shfl_xor(lv, off); l1 += __shfl_xor(l1, off); }
        if (j == 0) { logits[n] = lv + bgL; la1[n] = l1 + b1L; }
    }
    __syncthreads();
    if (valid && hasNext) {
        float a2 = bmL[j];
#pragma unroll
        for (int k = 0; k < 32; ++k) a2 += xnL[s][k] * WmL[k * 32 + j];
        m_out[n * 32 + j] = __float2bfloat16(lrelu(a2));
    }
}

// ---------------- per-graph softmax stats (+ zero pooled) ----------------
__global__ void k_gred(const float* __restrict__ logits, const int* __restrict__ goff,
                       float2* __restrict__ garr, float* __restrict__ pooled) {
    __shared__ float red[256];
    int g = blockIdx.x, tid = threadIdx.x;
    int s0 = goff[g], s1 = goff[g + 1];
    float lm = -INFINITY;
    for (int n = s0 + tid; n < s1; n += 256) lm = fmaxf(lm, logits[n]);
    red[tid] = lm;
    __syncthreads();
    for (int off = 128; off; off >>= 1) {
        if (tid < off) red[tid] = fmaxf(red[tid], red[tid + off]);
        __syncthreads();
    }
    float gmax = red[0];
    __syncthreads();
    float ls = 0.f;
    for (int n = s0 + tid; n < s1; n += 256) ls += expf(logits[n] - gmax);
    red[tid] = ls;
    __syncthreads();
    for (int off = 128; off; off >>= 1) {
        if (tid < off) red[tid] += red[tid + off];
        __syncthreads();
    }
    if (tid == 0) {
        float inv = (red[0] > 0.f) ? 1.f / red[0] : 0.f;
        garr[g] = make_float2(gmax, inv);
    }
    if (tid < 32) pooled[g * 32 + tid] = 0.f;
}

// ---------------- gate-weighted feature pooling (wide) ----------------
__global__ void k_pool(const float* __restrict__ x, const float* __restrict__ logits,
                       const int* __restrict__ batch, const float2* __restrict__ garr,
                       const float* __restrict__ Wf, const float* __restrict__ bf,
                       float* __restrict__ pooled, int N) {
    __shared__ float WL[1024];
    __shared__ float bL[32];
    __shared__ float xs[8][32];
    __shared__ float pl[4][32];
    __shared__ int gfirst;
    int tid = threadIdx.x;
    for (int t = tid; t < 1024; t += 256) WL[t] = Wf[t];
    if (tid < 32) bL[tid] = bf[tid];
    for (int t = tid; t < 128; t += 256) pl[t >> 5][t & 31] = 0.f;
    int n0 = blockIdx.x * 256;
    if (tid == 0) gfirst = batch[n0];
    int s = tid >> 5, j = tid & 31;
    __syncthreads();
    int gf = gfirst;
    for (int sub = 0; sub < 32; ++sub) {
        int n = n0 + sub * 8 + s;
        bool valid = n < N;
        __syncthreads();
        if (valid) xs[s][j] = x[n * 32 + j];
        __syncthreads();
        if (valid) {
            float f = bL[j];
#pragma unroll
            for (int k = 0; k < 32; ++k) f += xs[s][k] * WL[k * 32 + j];
            int g = batch[n];
            float2 gm = garr[g];
            float c = expf(logits[n] - gm.x) * gm.y * lrelu(f);
            int gl = g - gf;
            if (gl < 4) atomicAdd(&pl[gl][j], c);
            else atomicAdd(&pooled[g * 32 + j], c);
        }
    }
    __syncthreads();
    for (int t = tid; t < 128; t += 256) {
        float v = pl[t >> 5][t & 31];
        if (v != 0.f) atomicAdd(&pooled[(gf + (t >> 5)) * 32 + (t & 31)], v);
    }
}

// ---------------- xg transform + residual ----------------
__global__ void k_gupd(const float* __restrict__ pooled, const float* __restrict__ xg_in,
                       const float* __restrict__ Wt, const float* __restrict__ bt,
                       float* __restrict__ xg_out) {
    int idx = blockIdx.x * 256 + threadIdx.x;
    if (idx >= GG * 32) return;
    int g = idx >> 5, j = idx & 31;
    float acc = bt[j];
#pragma unroll
    for (int k = 0; k < 32; ++k) acc += pooled[g * 32 + k] * Wt[k * 32 + j];
#pragma unroll
    for (int k = 0; k < 32; ++k) acc += xg_in[g * 32 + k] * Wt[(32 + k) * 32 + j];
    xg_out[idx] = lrelu(acc) + xg_in[idx];
}

// ---------------- final: a1 softmax + value + a0 probs ----------------
__global__ void k_final(const float* __restrict__ logits, const int* __restrict__ goff,
                        const float* __restrict__ xg,
                        const void* __restrict__ Wv, const void* __restrict__ bv,
                        const void* __restrict__ Wa0, const void* __restrict__ ba0,
                        void* __restrict__ out, int N, const int* __restrict__ dtf) {
    __shared__ float red[256];
    int isf = *dtf;
    int g = blockIdx.x, tid = threadIdx.x;
    int s0 = goff[g], s1 = goff[g + 1];
    float lm = -INFINITY;
    for (int n = s0 + tid; n < s1; n += 256) lm = fmaxf(lm, logits[n]);
    red[tid] = lm;
    __syncthreads();
    for (int off = 128; off; off >>= 1) {
        if (tid < off) red[tid] = fmaxf(red[tid], red[tid + off]);
        __syncthreads();
    }
    float gmax = red[0];
    __syncthreads();
    float ls = 0.f;
    for (int n = s0 + tid; n < s1; n += 256) ls += expf(logits[n] - gmax);
    red[tid] = ls;
    __syncthreads();
    for (int off = 128; off; off >>= 1) {
        if (tid < off) red[tid] += red[tid + off];
        __syncthreads();
    }
    float inv = (red[0] > 0.f) ? 1.f / red[0] : 0.f;
    __syncthreads();
    for (int n = s0 + tid; n < s1; n += 256)
        stf(out, 384 + n, expf(logits[n] - gmax) * inv, isf);
    if (tid == 0) {
        float acc = ldf(bv, 0, isf);
        for (int k = 0; k < 32; ++k) acc += xg[g * 32 + k] * ldf(Wv, k, isf);
        stf(out, g, acc, isf);
        float l0 = ldf(ba0, 0, isf), l1 = ldf(ba0, 1, isf);
        for (int k = 0; k < 32; ++k) {
            float xv = xg[g * 32 + k];
            l0 += xv * ldf(Wa0, k * 2, isf);
            l1 += xv * ldf(Wa0, k * 2 + 1, isf);
        }
        float mm = fmaxf(l0, l1);
        float e0 = expf(l0 - mm), e1 = expf(l1 - mm);
        float si = 1.f / (e0 + e1);
        stf(out, 128 + 2 * g, e0 * si, isf);
        stf(out, 128 + 2 * g + 1, e1 * si, isf);
    }
}

extern "C" void kernel_launch(void* const* d_in, const int* in_sizes, int n_in,
                              void* d_out, int out_size, void* d_ws, size_t ws_size,
                              hipStream_t stream) {
    const void* nf      = d_in[0];
    const int*  eidx    = (const int*)d_in[1];
    const int*  batch   = (const int*)d_in[2];
    const void* W_embed = d_in[4];
    const void* b_embed = d_in[5];
    const void* Wm      = d_in[6];
    const void* bm      = d_in[7];
    const void* Wa      = d_in[8];
    const void* ba      = d_in[9];
    const void* Wgate   = d_in[10];
    const void* bgate   = d_in[11];
    const void* Wfeat   = d_in[12];
    const void* bfeat   = d_in[13];
    const void* Wt      = d_in[14];
    const void* bt      = d_in[15];
    const void* W_v     = d_in[16];
    const void* b_v     = d_in[17];
    const void* W_a0    = d_in[18];
    const void* b_a0    = d_in[19];
    const void* W_a1    = d_in[20];
    const void* b_a1    = d_in[21];

    const int N = in_sizes[0];
    const int E = in_sizes[1] / 2;
    const int nWm = in_sizes[6];  // 3*32*32 = 3072
    const int* src = eidx;
    const int* dst = eidx + E;
    const int B = (N + 255) >> 8;

    char* ws = (char*)d_ws;
    size_t off = 0;
    auto alloc = [&](size_t bytes) -> char* {
        char* p = ws + off;
        off = (off + bytes + 255) & ~(size_t)255;
        return p;
    };
    float*          x      = (float*)alloc((size_t)N * 32 * 4);
    // packed (E*8 B) aliases m_a+m_b (2 * N*32*2 B): packed dead after k_csr,
    // m first written by k_embed_msg which launches after k_csr.
    size_t mBytes  = (size_t)N * 32 * 2;
    size_t pkBytes = (size_t)E * 8;
    size_t rBytes  = (2 * mBytes > pkBytes) ? 2 * mBytes : pkBytes;
    char*  mRegion = alloc(rBytes);
    unsigned long long* packed = (unsigned long long*)mRegion;
    __hip_bfloat16*     m_a    = (__hip_bfloat16*)mRegion;
    __hip_bfloat16*     m_b    = (__hip_bfloat16*)(mRegion + mBytes);
    float*          logits = (float*)alloc((size_t)N * 4);
    float*          la1    = (float*)alloc((size_t)N * 4);
    unsigned*       indptr = (unsigned*)alloc((size_t)(N + 1) * 4);
    unsigned*       cursor = (unsigned*)alloc((size_t)N * 4);
    unsigned*       ssrc   = (unsigned*)alloc((size_t)(E + 8) * 4);  // +8 pad for clamped quads
    const int nb = (N + 255) / 256;
    unsigned*       bsum   = (unsigned*)alloc((size_t)nb * 4);
    unsigned*       boff   = (unsigned*)alloc((size_t)nb * 4);
    unsigned*       bcnt   = (unsigned*)alloc((size_t)(B + 1) * 4);
    unsigned*       bbase  = (unsigned*)alloc((size_t)(B + 1) * 4);
    unsigned*       bcur   = (unsigned*)alloc((size_t)(B + 1) * 4);
    int*            goff   = (int*)alloc((size_t)(GG + 1) * 4);
    float*          xg_a   = (float*)alloc((size_t)GG * 32 * 4);
    float*          xg_b   = (float*)alloc((size_t)GG * 32 * 4);
    float2*         garr   = (float2*)alloc((size_t)GG * 8);
    float*          pooled = (float*)alloc((size_t)GG * 32 * 4);
    int*            dtf    = (int*)alloc(256);
    float*          wcat   = (float*)alloc((size_t)WCAT_N * 4);

    const int nB_n  = (N + 255) / 256;
    const int nB_e  = (E + 255) / 256;
    const int nB_n8 = (N + 7) / 8;
    const int nB_ch = (E + CHUNK - 1) / CHUNK;

    hipMemsetAsync(xg_a, 0, (size_t)GG * 32 * 4, stream);
    hipMemsetAsync(bcnt, 0, (size_t)(B + 1) * 4, stream);

    k_detect<<<1, 256, 0, stream>>>((const unsigned short*)Wm, nWm, dtf);

    CvtArgs ca;
    const void* ps[12] = {Wm, bm, Wa, ba, Wgate, bgate, Wfeat, bfeat, Wt, bt, W_a1, b_a1};
    const int  offs[12] = {OFF_Wm, OFF_bm, OFF_Wa, OFF_ba, OFF_Wg, OFF_bg,
                           OFF_Wf, OFF_bf, OFF_Wt, OFF_bt, OFF_Wa1, OFF_ba1};
    const int  ns[12]  = {3072, 96, 9216, 96, 96, 3, 3072, 96, 6144, 96, 32, 1};
    for (int i = 0; i < 12; ++i) { ca.p[i] = ps[i]; ca.off[i] = offs[i]; ca.n[i] = ns[i]; }
    k_cvt_all<<<dim3(36, 12), 256, 0, stream>>>(ca, wcat, dtf);

    k_graph_off<<<nB_n, 256, 0, stream>>>(batch, goff, N);

    // CSR build first (packed aliases m buffers; m written after)
    if (B <= 2048) {
        k_bhist<<<nB_ch, 256, 0, stream>>>(dst, bcnt, E, B);
        k_bscan<<<1, 256, 0, stream>>>(bcnt, bbase, bcur, B, E);
        k_binA<<<nB_ch, 256, 0, stream>>>(src, dst, bcur, packed, E, B);
        k_csr<<<B, 256, 0, stream>>>(packed, bbase, indptr, ssrc, N, E);
    } else {
        hipMemsetAsync(cursor, 0, (size_t)N * 4, stream);
        k_hist<<<nB_e, 256, 0, stream>>>(dst, cursor, E);
        k_scan1<<<nb, 256, 0, stream>>>(cursor, indptr, bsum, N);
        k_scan2<<<1, 256, 0, stream>>>(bsum, boff, nb);
        k_scan3<<<nB_n, 256, 0, stream>>>(indptr, boff, cursor, N, E);
        k_scatter<<<nB_e, 256, 0, stream>>>(src, dst, cursor, ssrc, E);
    }

    // embed + step-0 message
    k_embed_msg<<<nB_n8, 256, 0, stream>>>(nf, W_embed, b_embed,
                                           wcat + OFF_Wm, wcat + OFF_bm, x, m_a, N, dtf);

    float* xg_cur = xg_a;
    float* xg_nxt = xg_b;
    __hip_bfloat16* m_cur = m_a;
    __hip_bfloat16* m_nxt = m_b;
    for (int i = 0; i < 3; ++i) {
        int hasNext = (i < 2) ? 1 : 0;
        k_step<<<nB_n8, 256, 0, stream>>>(x, m_cur, m_nxt, xg_cur, batch, indptr, ssrc,
                                          wcat + OFF_Wa + i * 3072, wcat + OFF_ba + i * 32,
                                          wcat + OFF_Wg + i * 32, wcat + OFF_bg + i,
                                          wcat + OFF_Wa1, wcat + OFF_ba1,
                                          wcat + OFF_Wm + (i + 1) * 1024,
                                          wcat + OFF_bm + (i + 1) * 32,
                                          logits, la1, N, hasNext);
        k_gred<<<GG, 256, 0, stream>>>(logits, goff, garr, pooled);
        k_pool<<<nB_n, 256, 0, stream>>>(x, logits, batch, garr,
                                         wcat + OFF_Wf + i * 1024, wcat + OFF_bf + i * 32,
                                         pooled, N);
        k_gupd<<<(GG * 32 + 255) / 256, 256, 0, stream>>>(pooled, xg_cur,
                                                          wcat + OFF_Wt + i * 2048,
                                                          wcat + OFF_bt + i * 32, xg_nxt);
        float* tmp = xg_cur; xg_cur = xg_nxt; xg_nxt = tmp;
        __hip_bfloat16* tm = m_cur; m_cur = m_nxt; m_nxt = tm;
    }

    k_final<<<GG, 256, 0, stream>>>(la1, goff, xg_cur, W_v, b_v, W_a0, b_a0,
                                    d_out, N, dtf);
}

// Round 7
// 881.110 us; speedup vs baseline: 1.8029x; 1.0434x over previous
//
#include <hip/hip_runtime.h>
#include <hip/hip_bf16.h>

#define GG 128
#define SLOPE 0.01f
#define CHUNK 8192
#define NPB 64   // nodes per block in k_step (weight staging amortization)

// wcat element offsets (f32 staged weights)
#define OFF_Wm   0
#define OFF_bm   3072
#define OFF_Wa   3168
#define OFF_ba   12384
#define OFF_Wg   12480
#define OFF_bg   12576
#define OFF_Wf   12592
#define OFF_bf   15664
#define OFF_Wt   15760
#define OFF_bt   21904
#define OFF_Wa1  22000
#define OFF_ba1  22032
#define WCAT_N   22048

__device__ __forceinline__ float lrelu(float v) { return v > 0.f ? v : SLOPE * v; }
__device__ __forceinline__ float b2f(__hip_bfloat16 v) { return __bfloat162float(v); }

__device__ __forceinline__ float ldf(const void* p, int i, int isf) {
    if (isf) return ((const float*)p)[i];
    return __bfloat162float(((const __hip_bfloat16*)p)[i]);
}
__device__ __forceinline__ void stf(void* p, int i, float v, int isf) {
    if (isf) ((float*)p)[i] = v;
    else ((__hip_bfloat16*)p)[i] = __float2bfloat16(v);
}

// bf16-pair unpack from u32 (bit ops only, no cvt)
__device__ __forceinline__ float bfLo(unsigned u) { return __uint_as_float(u << 16); }
__device__ __forceinline__ float bfHi(unsigned u) { return __uint_as_float(u & 0xFFFF0000u); }

// ---------------- dtype detection ----------------
__global__ void k_detect(const unsigned short* __restrict__ w, int n, int* __restrict__ flag) {
    __shared__ int bad;
    if (threadIdx.x == 0) bad = 0;
    __syncthreads();
    for (int t = threadIdx.x; t < n; t += 256) {
        unsigned short u = w[t];
        int e = (u >> 7) & 0xFF;
        if (e >= 141) bad = 1;  // benign same-value race
    }
    __syncthreads();
    if (threadIdx.x == 0) { flag[0] = bad; flag[32] = 1; }
}

// ---------------- one-shot weight staging to f32 ----------------
struct CvtArgs {
    const void* p[12];
    int off[12];
    int n[12];
};
__global__ void k_cvt_all(CvtArgs a, float* __restrict__ dst, const int* __restrict__ dtf) {
    int isf = *dtf;
    int seg = blockIdx.y;
    int i = blockIdx.x * 256 + threadIdx.x;
    if (i < a.n[seg]) dst[a.off[seg] + i] = ldf(a.p[seg], i, isf);
}

// ---------------- embed + step-0 message (fused) ----------------
__global__ void k_embed_msg(const void* __restrict__ nf, const void* __restrict__ We,
                            const void* __restrict__ be,
                            const float* __restrict__ Wm0, const float* __restrict__ bm0,
                            float* __restrict__ x, __hip_bfloat16* __restrict__ m, int N,
                            const int* __restrict__ dtf) {
    __shared__ float WL[1024];
    __shared__ float WeL[32], beL[32], bmL[32];
    __shared__ float xs[8][32];
    int isf = *dtf;
    int tid = threadIdx.x;
    for (int t = tid; t < 1024; t += 256) WL[t] = Wm0[t];
    if (tid < 32) { WeL[tid] = ldf(We, tid, isf); beL[tid] = ldf(be, tid, isf); bmL[tid] = bm0[tid]; }
    int s = tid >> 5, j = tid & 31;
    int n = blockIdx.x * 8 + s;
    __syncthreads();
    float xv = 0.f;
    if (n < N) {
        xv = lrelu(ldf(nf, n, isf) * WeL[j] + beL[j]);
        x[n * 32 + j] = xv;
        xs[s][j] = xv;
    }
    __syncthreads();
    if (n >= N) return;
    float acc = bmL[j];
#pragma unroll
    for (int k = 0; k < 32; ++k) acc += xs[s][k] * WL[k * 32 + j];
    m[n * 32 + j] = __float2bfloat16(lrelu(acc));
}

// ---------------- graph offsets from sorted batch ----------------
__global__ void k_graph_off(const int* __restrict__ batch, int* __restrict__ goff, int N) {
    int n = blockIdx.x * 256 + threadIdx.x;
    if (n >= N) return;
    int bn = batch[n];
    if (n == 0) {
        for (int g = 0; g <= bn; ++g) goff[g] = 0;
    } else {
        int bp = batch[n - 1];
        for (int g = bp + 1; g <= bn; ++g) goff[g] = n;
    }
    if (n == N - 1) {
        for (int g = bn + 1; g <= GG; ++g) goff[g] = N;
    }
}

// ---------------- fallback CSR build (B > 2048 only) ----------------
__global__ void k_hist(const int* __restrict__ dst, unsigned* __restrict__ deg, int E) {
    int e = blockIdx.x * 256 + threadIdx.x;
    if (e >= E) return;
    atomicAdd(&deg[dst[e]], 1u);
}
__global__ void k_scan1(const unsigned* __restrict__ deg, unsigned* __restrict__ excl,
                        unsigned* __restrict__ bsum, int N) {
    __shared__ unsigned s[256];
    int i = blockIdx.x * 256 + threadIdx.x;
    unsigned v = (i < N) ? deg[i] : 0u;
    s[threadIdx.x] = v;
    __syncthreads();
    for (int off = 1; off < 256; off <<= 1) {
        unsigned t = (threadIdx.x >= (unsigned)off) ? s[threadIdx.x - off] : 0u;
        __syncthreads();
        s[threadIdx.x] += t;
        __syncthreads();
    }
    if (i < N) excl[i] = s[threadIdx.x] - v;
    if (threadIdx.x == 255) bsum[blockIdx.x] = s[255];
}
__global__ void k_scan2(const unsigned* __restrict__ bsum, unsigned* __restrict__ boff, int nb) {
    __shared__ unsigned s[256];
    __shared__ unsigned carry;
    if (threadIdx.x == 0) carry = 0u;
    __syncthreads();
    for (int base = 0; base < nb; base += 256) {
        int i = base + threadIdx.x;
        unsigned v = (i < nb) ? bsum[i] : 0u;
        s[threadIdx.x] = v;
        __syncthreads();
        for (int off = 1; off < 256; off <<= 1) {
            unsigned t = (threadIdx.x >= (unsigned)off) ? s[threadIdx.x - off] : 0u;
            __syncthreads();
            s[threadIdx.x] += t;
            __syncthreads();
        }
        if (i < nb) boff[i] = carry + s[threadIdx.x] - v;
        __syncthreads();
        if (threadIdx.x == 0) carry += s[255];
        __syncthreads();
    }
}
__global__ void k_scan3(unsigned* __restrict__ indptr, const unsigned* __restrict__ boff,
                        unsigned* __restrict__ cursor, int N, int E) {
    int i = blockIdx.x * 256 + threadIdx.x;
    if (i >= N) return;
    unsigned v = indptr[i] + boff[i >> 8];
    indptr[i] = v;
    cursor[i] = v;
    if (i == 0) indptr[N] = (unsigned)E;
}
__global__ void k_scatter(const int* __restrict__ src, const int* __restrict__ dst,
                          unsigned* __restrict__ cursor, unsigned* __restrict__ ssrc, int E) {
    int e = blockIdx.x * 256 + threadIdx.x;
    if (e >= E) return;
    unsigned pos = atomicAdd(&cursor[dst[e]], 1u);
    ssrc[pos] = (unsigned)src[e];
}

// ---------------- bucketed CSR build ----------------
__global__ void k_bhist(const int* __restrict__ dst, unsigned* __restrict__ bcnt, int E, int B) {
    __shared__ unsigned h[2048];
    for (int t = threadIdx.x; t < B; t += 256) h[t] = 0;
    __syncthreads();
    int start = blockIdx.x * CHUNK, end = min(E, start + CHUNK);
    for (int e = start + threadIdx.x; e < end; e += 256)
        atomicAdd(&h[dst[e] >> 8], 1u);
    __syncthreads();
    for (int t = threadIdx.x; t < B; t += 256)
        if (h[t]) atomicAdd(&bcnt[t], h[t]);
}

__global__ void k_bscan(const unsigned* __restrict__ bcnt, unsigned* __restrict__ bbase,
                        unsigned* __restrict__ bcur, int B, int E) {
    __shared__ unsigned s[256];
    __shared__ unsigned carry;
    if (threadIdx.x == 0) carry = 0u;
    __syncthreads();
    for (int base = 0; base < B; base += 256) {
        int i = base + threadIdx.x;
        unsigned v = (i < B) ? bcnt[i] : 0u;
        s[threadIdx.x] = v;
        __syncthreads();
        for (int off = 1; off < 256; off <<= 1) {
            unsigned t = (threadIdx.x >= (unsigned)off) ? s[threadIdx.x - off] : 0u;
            __syncthreads();
            s[threadIdx.x] += t;
            __syncthreads();
        }
        if (i < B) {
            unsigned ex = carry + s[threadIdx.x] - v;
            bbase[i] = ex;
            bcur[i] = ex;
        }
        __syncthreads();
        if (threadIdx.x == 0) carry += s[255];
        __syncthreads();
    }
    if (threadIdx.x == 0) bbase[B] = (unsigned)E;
}

__global__ void k_binA(const int* __restrict__ src, const int* __restrict__ dst,
                       unsigned* __restrict__ bcur, unsigned long long* __restrict__ packed,
                       int E, int B) {
    __shared__ unsigned h[2048];
    __shared__ unsigned pos[2048];
    for (int t = threadIdx.x; t < B; t += 256) h[t] = 0;
    __syncthreads();
    int start = blockIdx.x * CHUNK, end = min(E, start + CHUNK);
    for (int e = start + threadIdx.x; e < end; e += 256)
        atomicAdd(&h[dst[e] >> 8], 1u);
    __syncthreads();
    for (int t = threadIdx.x; t < B; t += 256)
        pos[t] = h[t] ? atomicAdd(&bcur[t], h[t]) : 0u;
    __syncthreads();
    for (int e = start + threadIdx.x; e < end; e += 256) {
        int d = dst[e];
        unsigned p = atomicAdd(&pos[d >> 8], 1u);
        packed[p] = ((unsigned long long)(unsigned)d << 32) | (unsigned)src[e];
    }
}

// per-bucket: LDS degree count + scan -> indptr, then bucket-local scatter
__global__ void k_csr(const unsigned long long* __restrict__ packed,
                      const unsigned* __restrict__ bbase,
                      unsigned* __restrict__ indptr,
                      unsigned* __restrict__ ssrc, int N, int E) {
    __shared__ unsigned deg[256];
    __shared__ unsigned scn[256];
    __shared__ unsigned cur[256];
    int g = blockIdx.x, tid = threadIdx.x;
    int n0 = g << 8;
    int cnt = min(256, N - n0);
    deg[tid] = 0;
    __syncthreads();
    unsigned e0 = bbase[g], e1 = bbase[g + 1];
    for (unsigned e = e0 + tid; e < e1; e += 256) {
        int d = (int)(packed[e] >> 32);
        atomicAdd(&deg[d - n0], 1u);
    }
    __syncthreads();
    unsigned v = deg[tid];
    scn[tid] = v;
    __syncthreads();
    for (int off = 1; off < 256; off <<= 1) {
        unsigned t = (tid >= off) ? scn[tid - off] : 0u;
        __syncthreads();
        scn[tid] += t;
        __syncthreads();
    }
    unsigned start = e0 + scn[tid] - v;
    if (tid < cnt) { indptr[n0 + tid] = start; cur[tid] = start; }
    if (g == (int)gridDim.x - 1 && tid == 0) indptr[N] = (unsigned)E;
    __syncthreads();
    for (unsigned e = e0 + tid; e < e1; e += 256) {
        unsigned long long pk = packed[e];
        int d = (int)(pk >> 32);
        unsigned p = atomicAdd(&cur[d - n0], 1u);
        ssrc[p] = (unsigned)pk;
    }
}

// ---------------- fused step: gather-max + f_agg + logits + next message ----------------
// 64 nodes/block (weights staged once). Gather: 4 lanes/edge, uint4 (16B) loads,
// 16 edges in flight per 32-lane node-group; clamp-duplicate tail (idempotent max).
__global__ void k_step(float* __restrict__ x, const __hip_bfloat16* __restrict__ m_in,
                       __hip_bfloat16* __restrict__ m_out,
                       const float* __restrict__ xg, const int* __restrict__ batch,
                       const unsigned* __restrict__ indptr, const unsigned* __restrict__ ssrc,
                       const float* __restrict__ Wa, const float* __restrict__ ba,
                       const float* __restrict__ Wg, const float* __restrict__ bg,
                       const float* __restrict__ Wa1, const float* __restrict__ ba1,
                       const float* __restrict__ Wm_nx, const float* __restrict__ bm_nx,
                       float* __restrict__ logits, float* __restrict__ la1,
                       int N, int hasNext) {
    __shared__ float WL[3072];
    __shared__ float WmL[1024];
    __shared__ float zL[8][96];
    __shared__ float xnL[8][32];
    __shared__ float baL[32], WgL[32], W1L[32], bmL[32];
    __shared__ float bgL, b1L;
    int tid = threadIdx.x;
    for (int t = tid; t < 3072; t += 256) WL[t] = Wa[t];
    if (hasNext) {
        for (int t = tid; t < 1024; t += 256) WmL[t] = Wm_nx[t];
        if (tid < 32) bmL[tid] = bm_nx[tid];
    }
    if (tid < 32) { baL[tid] = ba[tid]; WgL[tid] = Wg[tid]; W1L[tid] = Wa1[tid]; }
    if (tid == 0) { bgL = bg[0]; b1L = ba1[0]; }
    int s = tid >> 5, j = tid & 31;
    int c = j & 3;        // 16B chunk within 64B row (features 8c..8c+7)
    int eo = j >> 2;      // edge slot 0..7 within octet
    const uint4* m4 = (const uint4*)m_in;
    int nbase = blockIdx.x * NPB;
    __syncthreads();
    // NOTE: zL/xnL rows are private to each 32-lane group (half-wave) ->
    // wave-synchronous LDS, no barriers needed inside the sub loop.
    for (int sub = 0; sub < NPB / 8; ++sub) {
        int n = nbase + sub * 8 + s;
        bool valid = n < N;
        if (valid) {
            zL[s][j] = x[n * 32 + j];
            zL[s][32 + j] = xg[batch[n] * 32 + j];
        }
        unsigned st = 0, en = 0;
        if (valid) { st = indptr[n]; en = indptr[n + 1]; }
        float a[8];
#pragma unroll
        for (int t = 0; t < 8; ++t) a[t] = -INFINITY;
        if (en > st) {
            unsigned last = en - 1;
            for (unsigned base = st; base < en; base += 16) {
                unsigned eA = min(base + eo, last);
                unsigned eB = min(base + 8 + eo, last);
                unsigned sA = ssrc[eA];
                unsigned sB = ssrc[eB];
                uint4 vA = m4[sA * 4 + c];
                uint4 vB = m4[sB * 4 + c];
                a[0] = fmaxf(a[0], fmaxf(bfLo(vA.x), bfLo(vB.x)));
                a[1] = fmaxf(a[1], fmaxf(bfHi(vA.x), bfHi(vB.x)));
                a[2] = fmaxf(a[2], fmaxf(bfLo(vA.y), bfLo(vB.y)));
                a[3] = fmaxf(a[3], fmaxf(bfHi(vA.y), bfHi(vB.y)));
                a[4] = fmaxf(a[4], fmaxf(bfLo(vA.z), bfLo(vB.z)));
                a[5] = fmaxf(a[5], fmaxf(bfHi(vA.z), bfHi(vB.z)));
                a[6] = fmaxf(a[6], fmaxf(bfLo(vA.w), bfLo(vB.w)));
                a[7] = fmaxf(a[7], fmaxf(bfHi(vA.w), bfHi(vB.w)));
            }
        }
        // combine the 8 edge slots (xor over lane bits 2..4, within node-group)
#pragma unroll
        for (int t = 0; t < 8; ++t) {
            a[t] = fmaxf(a[t], __shfl_xor(a[t], 4));
            a[t] = fmaxf(a[t], __shfl_xor(a[t], 8));
            a[t] = fmaxf(a[t], __shfl_xor(a[t], 16));
        }
        if (valid && eo == 0) {
            bool empty = (st == en);
#pragma unroll
            for (int t = 0; t < 8; ++t)
                zL[s][64 + c * 8 + t] = empty ? 0.f : a[t];
        }
        if (valid) {
            float acc = baL[j];
#pragma unroll
            for (int k = 0; k < 96; ++k) acc += zL[s][k] * WL[k * 32 + j];
            float xn = lrelu(acc) + zL[s][j];
            x[n * 32 + j] = xn;
            xnL[s][j] = xn;
            float lv = xn * WgL[j];
            float l1 = xn * W1L[j];
#pragma unroll
            for (int off = 16; off; off >>= 1) { lv += __shfl_xor(lv, off); l1 += __shfl_xor(l1, off); }
            if (j == 0) { logits[n] = lv + bgL; la1[n] = l1 + b1L; }
            if (hasNext) {
                float a2 = bmL[j];
#pragma unroll
                for (int k = 0; k < 32; ++k) a2 += xnL[s][k] * WmL[k * 32 + j];
                m_out[n * 32 + j] = __float2bfloat16(lrelu(a2));
            }
        }
    }
}

// ---------------- per-graph softmax stats (+ zero pooled) ----------------
__global__ void k_gred(const float* __restrict__ logits, const int* __restrict__ goff,
                       float2* __restrict__ garr, float* __restrict__ pooled) {
    __shared__ float red[256];
    int g = blockIdx.x, tid = threadIdx.x;
    int s0 = goff[g], s1 = goff[g + 1];
    float lm = -INFINITY;
    for (int n = s0 + tid; n < s1; n += 256) lm = fmaxf(lm, logits[n]);
    red[tid] = lm;
    __syncthreads();
    for (int off = 128; off; off >>= 1) {
        if (tid < off) red[tid] = fmaxf(red[tid], red[tid + off]);
        __syncthreads();
    }
    float gmax = red[0];
    __syncthreads();
    float ls = 0.f;
    for (int n = s0 + tid; n < s1; n += 256) ls += expf(logits[n] - gmax);
    red[tid] = ls;
    __syncthreads();
    for (int off = 128; off; off >>= 1) {
        if (tid < off) red[tid] += red[tid + off];
        __syncthreads();
    }
    if (tid == 0) {
        float inv = (red[0] > 0.f) ? 1.f / red[0] : 0.f;
        garr[g] = make_float2(gmax, inv);
    }
    if (tid < 32) pooled[g * 32 + tid] = 0.f;
}

// ---------------- gate-weighted feature pooling (wide) ----------------
__global__ void k_pool(const float* __restrict__ x, const float* __restrict__ logits,
                       const int* __restrict__ batch, const float2* __restrict__ garr,
                       const float* __restrict__ Wf, const float* __restrict__ bf,
                       float* __restrict__ pooled, int N) {
    __shared__ float WL[1024];
    __shared__ float bL[32];
    __shared__ float xs[8][32];
    __shared__ float pl[4][32];
    __shared__ int gfirst;
    int tid = threadIdx.x;
    for (int t = tid; t < 1024; t += 256) WL[t] = Wf[t];
    if (tid < 32) bL[tid] = bf[tid];
    for (int t = tid; t < 128; t += 256) pl[t >> 5][t & 31] = 0.f;
    int n0 = blockIdx.x * 256;
    if (tid == 0) gfirst = batch[n0];
    int s = tid >> 5, j = tid & 31;
    __syncthreads();
    int gf = gfirst;
    for (int sub = 0; sub < 32; ++sub) {
        int n = n0 + sub * 8 + s;
        bool valid = n < N;
        __syncthreads();
        if (valid) xs[s][j] = x[n * 32 + j];
        __syncthreads();
        if (valid) {
            float f = bL[j];
#pragma unroll
            for (int k = 0; k < 32; ++k) f += xs[s][k] * WL[k * 32 + j];
            int g = batch[n];
            float2 gm = garr[g];
            float c = expf(logits[n] - gm.x) * gm.y * lrelu(f);
            int gl = g - gf;
            if (gl < 4) atomicAdd(&pl[gl][j], c);
            else atomicAdd(&pooled[g * 32 + j], c);
        }
    }
    __syncthreads();
    for (int t = tid; t < 128; t += 256) {
        float v = pl[t >> 5][t & 31];
        if (v != 0.f) atomicAdd(&pooled[(gf + (t >> 5)) * 32 + (t & 31)], v);
    }
}

// ---------------- xg transform + residual ----------------
__global__ void k_gupd(const float* __restrict__ pooled, const float* __restrict__ xg_in,
                       const float* __restrict__ Wt, const float* __restrict__ bt,
                       float* __restrict__ xg_out) {
    int idx = blockIdx.x * 256 + threadIdx.x;
    if (idx >= GG * 32) return;
    int g = idx >> 5, j = idx & 31;
    float acc = bt[j];
#pragma unroll
    for (int k = 0; k < 32; ++k) acc += pooled[g * 32 + k] * Wt[k * 32 + j];
#pragma unroll
    for (int k = 0; k < 32; ++k) acc += xg_in[g * 32 + k] * Wt[(32 + k) * 32 + j];
    xg_out[idx] = lrelu(acc) + xg_in[idx];
}

// ---------------- final: a1 softmax + value + a0 probs ----------------
__global__ void k_final(const float* __restrict__ logits, const int* __restrict__ goff,
                        const float* __restrict__ xg,
                        const void* __restrict__ Wv, const void* __restrict__ bv,
                        const void* __restrict__ Wa0, const void* __restrict__ ba0,
                        void* __restrict__ out, int N, const int* __restrict__ dtf) {
    __shared__ float red[256];
    int isf = *dtf;
    int g = blockIdx.x, tid = threadIdx.x;
    int s0 = goff[g], s1 = goff[g + 1];
    float lm = -INFINITY;
    for (int n = s0 + tid; n < s1; n += 256) lm = fmaxf(lm, logits[n]);
    red[tid] = lm;
    __syncthreads();
    for (int off = 128; off; off >>= 1) {
        if (tid < off) red[tid] = fmaxf(red[tid], red[tid + off]);
        __syncthreads();
    }
    float gmax = red[0];
    __syncthreads();
    float ls = 0.f;
    for (int n = s0 + tid; n < s1; n += 256) ls += expf(logits[n] - gmax);
    red[tid] = ls;
    __syncthreads();
    for (int off = 128; off; off >>= 1) {
        if (tid < off) red[tid] += red[tid + off];
        __syncthreads();
    }
    float inv = (red[0] > 0.f) ? 1.f / red[0] : 0.f;
    __syncthreads();
    for (int n = s0 + tid; n < s1; n += 256)
        stf(out, 384 + n, expf(logits[n] - gmax) * inv, isf);
    if (tid == 0) {
        float acc = ldf(bv, 0, isf);
        for (int k = 0; k < 32; ++k) acc += xg[g * 32 + k] * ldf(Wv, k, isf);
        stf(out, g, acc, isf);
        float l0 = ldf(ba0, 0, isf), l1 = ldf(ba0, 1, isf);
        for (int k = 0; k < 32; ++k) {
            float xv = xg[g * 32 + k];
            l0 += xv * ldf(Wa0, k * 2, isf);
            l1 += xv * ldf(Wa0, k * 2 + 1, isf);
        }
        float mm = fmaxf(l0, l1);
        float e0 = expf(l0 - mm), e1 = expf(l1 - mm);
        float si = 1.f / (e0 + e1);
        stf(out, 128 + 2 * g, e0 * si, isf);
        stf(out, 128 + 2 * g + 1, e1 * si, isf);
    }
}

extern "C" void kernel_launch(void* const* d_in, const int* in_sizes, int n_in,
                              void* d_out, int out_size, void* d_ws, size_t ws_size,
                              hipStream_t stream) {
    const void* nf      = d_in[0];
    const int*  eidx    = (const int*)d_in[1];
    const int*  batch   = (const int*)d_in[2];
    const void* W_embed = d_in[4];
    const void* b_embed = d_in[5];
    const void* Wm      = d_in[6];
    const void* bm      = d_in[7];
    const void* Wa      = d_in[8];
    const void* ba      = d_in[9];
    const void* Wgate   = d_in[10];
    const void* bgate   = d_in[11];
    const void* Wfeat   = d_in[12];
    const void* bfeat   = d_in[13];
    const void* Wt      = d_in[14];
    const void* bt      = d_in[15];
    const void* W_v     = d_in[16];
    const void* b_v     = d_in[17];
    const void* W_a0    = d_in[18];
    const void* b_a0    = d_in[19];
    const void* W_a1    = d_in[20];
    const void* b_a1    = d_in[21];

    const int N = in_sizes[0];
    const int E = in_sizes[1] / 2;
    const int nWm = in_sizes[6];  // 3*32*32 = 3072
    const int* src = eidx;
    const int* dst = eidx + E;
    const int B = (N + 255) >> 8;

    char* ws = (char*)d_ws;
    size_t off = 0;
    auto alloc = [&](size_t bytes) -> char* {
        char* p = ws + off;
        off = (off + bytes + 255) & ~(size_t)255;
        return p;
    };
    float*          x      = (float*)alloc((size_t)N * 32 * 4);
    // packed (E*8 B) aliases m_a+m_b (2 * N*32*2 B): packed dead after k_csr,
    // m first written by k_embed_msg which launches after k_csr.
    size_t mBytes  = (size_t)N * 32 * 2;
    size_t pkBytes = (size_t)E * 8;
    size_t rBytes  = (2 * mBytes > pkBytes) ? 2 * mBytes : pkBytes;
    char*  mRegion = alloc(rBytes);
    unsigned long long* packed = (unsigned long long*)mRegion;
    __hip_bfloat16*     m_a    = (__hip_bfloat16*)mRegion;
    __hip_bfloat16*     m_b    = (__hip_bfloat16*)(mRegion + mBytes);
    float*          logits = (float*)alloc((size_t)N * 4);
    float*          la1    = (float*)alloc((size_t)N * 4);
    unsigned*       indptr = (unsigned*)alloc((size_t)(N + 1) * 4);
    unsigned*       cursor = (unsigned*)alloc((size_t)N * 4);
    unsigned*       ssrc   = (unsigned*)alloc((size_t)(E + 16) * 4);
    const int nb = (N + 255) / 256;
    unsigned*       bsum   = (unsigned*)alloc((size_t)nb * 4);
    unsigned*       boff   = (unsigned*)alloc((size_t)nb * 4);
    unsigned*       bcnt   = (unsigned*)alloc((size_t)(B + 1) * 4);
    unsigned*       bbase  = (unsigned*)alloc((size_t)(B + 1) * 4);
    unsigned*       bcur   = (unsigned*)alloc((size_t)(B + 1) * 4);
    int*            goff   = (int*)alloc((size_t)(GG + 1) * 4);
    float*          xg_a   = (float*)alloc((size_t)GG * 32 * 4);
    float*          xg_b   = (float*)alloc((size_t)GG * 32 * 4);
    float2*         garr   = (float2*)alloc((size_t)GG * 8);
    float*          pooled = (float*)alloc((size_t)GG * 32 * 4);
    int*            dtf    = (int*)alloc(256);
    float*          wcat   = (float*)alloc((size_t)WCAT_N * 4);

    const int nB_n  = (N + 255) / 256;
    const int nB_e  = (E + 255) / 256;
    const int nB_n8 = (N + 7) / 8;
    const int nB_st = (N + NPB - 1) / NPB;
    const int nB_ch = (E + CHUNK - 1) / CHUNK;

    hipMemsetAsync(xg_a, 0, (size_t)GG * 32 * 4, stream);
    hipMemsetAsync(bcnt, 0, (size_t)(B + 1) * 4, stream);

    k_detect<<<1, 256, 0, stream>>>((const unsigned short*)Wm, nWm, dtf);

    CvtArgs ca;
    const void* ps[12] = {Wm, bm, Wa, ba, Wgate, bgate, Wfeat, bfeat, Wt, bt, W_a1, b_a1};
    const int  offs[12] = {OFF_Wm, OFF_bm, OFF_Wa, OFF_ba, OFF_Wg, OFF_bg,
                           OFF_Wf, OFF_bf, OFF_Wt, OFF_bt, OFF_Wa1, OFF_ba1};
    const int  ns[12]  = {3072, 96, 9216, 96, 96, 3, 3072, 96, 6144, 96, 32, 1};
    for (int i = 0; i < 12; ++i) { ca.p[i] = ps[i]; ca.off[i] = offs[i]; ca.n[i] = ns[i]; }
    k_cvt_all<<<dim3(36, 12), 256, 0, stream>>>(ca, wcat, dtf);

    k_graph_off<<<nB_n, 256, 0, stream>>>(batch, goff, N);

    // CSR build first (packed aliases m buffers; m written after)
    if (B <= 2048) {
        k_bhist<<<nB_ch, 256, 0, stream>>>(dst, bcnt, E, B);
        k_bscan<<<1, 256, 0, stream>>>(bcnt, bbase, bcur, B, E);
        k_binA<<<nB_ch, 256, 0, stream>>>(src, dst, bcur, packed, E, B);
        k_csr<<<B, 256, 0, stream>>>(packed, bbase, indptr, ssrc, N, E);
    } else {
        hipMemsetAsync(cursor, 0, (size_t)N * 4, stream);
        k_hist<<<nB_e, 256, 0, stream>>>(dst, cursor, E);
        k_scan1<<<nb, 256, 0, stream>>>(cursor, indptr, bsum, N);
        k_scan2<<<1, 256, 0, stream>>>(bsum, boff, nb);
        k_scan3<<<nB_n, 256, 0, stream>>>(indptr, boff, cursor, N, E);
        k_scatter<<<nB_e, 256, 0, stream>>>(src, dst, cursor, ssrc, E);
    }

    // embed + step-0 message
    k_embed_msg<<<nB_n8, 256, 0, stream>>>(nf, W_embed, b_embed,
                                           wcat + OFF_Wm, wcat + OFF_bm, x, m_a, N, dtf);

    float* xg_cur = xg_a;
    float* xg_nxt = xg_b;
    __hip_bfloat16* m_cur = m_a;
    __hip_bfloat16* m_nxt = m_b;
    for (int i = 0; i < 3; ++i) {
        int hasNext = (i < 2) ? 1 : 0;
        k_step<<<nB_st, 256, 0, stream>>>(x, m_cur, m_nxt, xg_cur, batch, indptr, ssrc,
                                          wcat + OFF_Wa + i * 3072, wcat + OFF_ba + i * 32,
                                          wcat + OFF_Wg + i * 32, wcat + OFF_bg + i,
                                          wcat + OFF_Wa1, wcat + OFF_ba1,
                                          wcat + OFF_Wm + (i + 1) * 1024,
                                          wcat + OFF_bm + (i + 1) * 32,
                                          logits, la1, N, hasNext);
        k_gred<<<GG, 256, 0, stream>>>(logits, goff, garr, pooled);
        k_pool<<<nB_n, 256, 0, stream>>>(x, logits, batch, garr,
                                         wcat + OFF_Wf + i * 1024, wcat + OFF_bf + i * 32,
                                         pooled, N);
        k_gupd<<<(GG * 32 + 255) / 256, 256, 0, stream>>>(pooled, xg_cur,
                                                          wcat + OFF_Wt + i * 2048,
                                                          wcat + OFF_bt + i * 32, xg_nxt);
        float* tmp = xg_cur; xg_cur = xg_nxt; xg_nxt = tmp;
        __hip_bfloat16* tm = m_cur; m_cur = m_nxt; m_nxt = tm;
    }

    k_final<<<GG, 256, 0, stream>>>(la1, goff, xg_cur, W_v, b_v, W_a0, b_a0,
                                    d_out, N, dtf);
}